// Round 5
// baseline (319.999 us; speedup 1.0000x reference)
//
#include <hip/hip_runtime.h>
#include <math.h>

#define NPOS 65536          // D*H*W = 16*64*64
#define DD 16
#define HHH 64
#define WWW 64
#define NCHUNK 128

// ---------------- K0: transpose weights to [in][out] layouts ----------------
__global__ void k0_transpose(const float* __restrict__ Wq, const float* __restrict__ Wr,
                             const float* __restrict__ Wf, const float* __restrict__ Wp,
                             float* __restrict__ Wqt, float* __restrict__ Wrt,
                             float* __restrict__ Wft, float* __restrict__ Wpt) {
    int idx = blockIdx.x * 256 + threadIdx.x;
    if (idx < 192*64) { int oc = idx / 64, ic = idx % 64; Wqt[ic*192 + oc] = Wq[idx]; }
    int i2 = idx - 192*64;
    if (i2 >= 0 && i2 < 64*64) { int oc = i2 / 64, c = i2 % 64; Wrt[c*64 + oc] = Wr[i2]; }
    int i3 = i2 - 64*64;
    if (i3 >= 0 && i3 < 64*128) { int oc = i3 / 128, c = i3 % 128; Wft[c*64 + oc] = Wf[i3]; }
    int i4 = i3 - 64*128;
    if (i4 >= 0 && i4 < 64*64) { int oc = i4 / 64, c = i4 % 64; Wpt[c*64 + oc] = Wp[i4]; }
}

// ---------------- K1: pointwise qkv conv (192 out x 64 in) ----------------
__global__ __launch_bounds__(256) void k1_qkv(const float* __restrict__ x,
        const float* __restrict__ Wqt, const float* __restrict__ bq,
        float* __restrict__ qkv) {
    __shared__ float xs[64 * 256];
    const int tid = threadIdx.x;
    const int blk = blockIdx.x;
    const int b = blk >> 8;                 // 256 blocks per batch
    const int n0 = (blk & 255) << 8;
    const float* xb = x + ((long long)b * 64) * NPOS + n0;
    for (int ic = 0; ic < 64; ++ic)
        xs[ic * 256 + tid] = xb[(long long)ic * NPOS + tid];
    __syncthreads();
    float* outb = qkv + ((long long)b * 192) * NPOS + n0 + tid;
    for (int chunk = 0; chunk < 3; ++chunk) {
        float acc[64];
        #pragma unroll
        for (int o = 0; o < 64; ++o) acc[o] = bq[chunk * 64 + o];
        for (int ic = 0; ic < 64; ++ic) {
            float xv = xs[ic * 256 + tid];
            #pragma unroll
            for (int o = 0; o < 64; ++o)
                acc[o] = fmaf(Wqt[ic * 192 + chunk * 64 + o], xv, acc[o]);
        }
        #pragma unroll
        for (int o = 0; o < 64; ++o)
            outb[(long long)(chunk * 64 + o) * NPOS] = acc[o];
    }
}

// ---------------- K2: depthwise 3x3x3 conv via LDS stencil tile ----------------
__global__ __launch_bounds__(256) void k2_dw(const float* __restrict__ qkv,
        const float* __restrict__ Wd, const float* __restrict__ bd,
        float* __restrict__ qkv2) {
    __shared__ __align__(16) float tile[108 * 84];
    __shared__ float wsh[28];
    const int tid = threadIdx.x;
    const int bc  = blockIdx.x >> 4;        // 0..383 = b*192 + c
    const int sub = blockIdx.x & 15;
    const int d0  = (sub >> 2) << 2;        // 0,4,8,12
    const int h0  = (sub & 3) << 4;         // 0,16,32,48
    const int c   = bc % 192;

    if (tid < 27) wsh[tid] = Wd[c * 27 + tid];
    if (tid == 31) wsh[27] = bd[c];

    const float* in = qkv + (long long)bc * NPOS;
    for (int r = tid; r < 108; r += 256) {
        tile[r * 84 + 3]  = 0.f;
        tile[r * 84 + 68] = 0.f;
    }
    for (int i = tid; i < 1728; i += 256) {
        const int r = i >> 4, q = i & 15;
        const int dd = r / 18;              // 0..5
        const int hh = r - dd * 18;         // 0..17
        const int d = d0 + dd - 1;
        const int h = h0 + hh - 1;
        float4 v = make_float4(0.f, 0.f, 0.f, 0.f);
        if (d >= 0 && d < DD && h >= 0 && h < HHH)
            v = *(const float4*)(in + (d << 12) + (h << 6) + (q << 2));
        *(float4*)(tile + r * 84 + 4 + (q << 2)) = v;
    }
    __syncthreads();

    float wreg[27];
    #pragma unroll
    for (int s = 0; s < 27; ++s) wreg[s] = wsh[s];
    const float bias = wsh[27];

    const int wg  = tid & 7;
    const int w0  = wg << 3;                // 8 outputs along w
    const int rid = tid >> 3;               // 0..31
    const int oh  = rid & 15;               // 0..15
    const int od  = (rid >> 4) << 1;        // 0 or 2 (d-pair base)

    float acc0[8], acc1[8];
    #pragma unroll
    for (int j = 0; j < 8; ++j) { acc0[j] = bias; acc1[j] = bias; }

    #pragma unroll
    for (int kh = 0; kh < 3; ++kh) {
        #pragma unroll
        for (int dd = 0; dd < 4; ++dd) {
            const float* row = tile + ((od + dd) * 18 + oh + kh) * 84 + w0;
            const float4 q0 = *(const float4*)(row);
            const float4 q1 = *(const float4*)(row + 4);
            const float4 q2 = *(const float4*)(row + 8);
            const float4 q3 = *(const float4*)(row + 12);
            const float e0 = q0.w, e1 = q1.x, e2 = q1.y, e3 = q1.z, e4 = q1.w;
            const float e5 = q2.x, e6 = q2.y, e7 = q2.z, e8 = q2.w, e9 = q3.x;
            const float ee[10] = {e0,e1,e2,e3,e4,e5,e6,e7,e8,e9};
            if (dd < 3) {
                const float W0 = wreg[dd * 9 + kh * 3 + 0];
                const float W1 = wreg[dd * 9 + kh * 3 + 1];
                const float W2 = wreg[dd * 9 + kh * 3 + 2];
                #pragma unroll
                for (int j = 0; j < 8; ++j)
                    acc0[j] = fmaf(W0, ee[j], fmaf(W1, ee[j+1], fmaf(W2, ee[j+2], acc0[j])));
            }
            if (dd > 0) {
                const float W0 = wreg[(dd-1) * 9 + kh * 3 + 0];
                const float W1 = wreg[(dd-1) * 9 + kh * 3 + 1];
                const float W2 = wreg[(dd-1) * 9 + kh * 3 + 2];
                #pragma unroll
                for (int j = 0; j < 8; ++j)
                    acc1[j] = fmaf(W0, ee[j], fmaf(W1, ee[j+1], fmaf(W2, ee[j+2], acc1[j])));
            }
        }
    }
    float* outp = qkv2 + (long long)bc * NPOS + ((d0 + od) << 12) + ((h0 + oh) << 6) + w0;
    *(float4*)(outp)          = make_float4(acc0[0], acc0[1], acc0[2], acc0[3]);
    *(float4*)(outp + 4)      = make_float4(acc0[4], acc0[5], acc0[6], acc0[7]);
    *(float4*)(outp + 4096)     = make_float4(acc1[0], acc1[1], acc1[2], acc1[3]);
    *(float4*)(outp + 4096 + 4) = make_float4(acc1[4], acc1[5], acc1[6], acc1[7]);
}

// ---------------- K3: Gram partials: per (b,h,chunk) -> 64 qk + 8 qq + 8 kk ----------------
__global__ __launch_bounds__(256) void k3_gram(const float* __restrict__ qkv2,
                                               float* __restrict__ partial) {
    const int blk = blockIdx.x;
    const int chunk = blk & (NCHUNK - 1);
    const int bh = blk >> 7;                  // 0..15
    const int b = bh >> 3, h = bh & 7;
    const float* qb = qkv2 + ((long long)b * 192 + h * 8) * NPOS;
    const float* kb = qb + 64 * NPOS;
    const int npc = NPOS / NCHUNK;            // 512
    const int n0 = chunk * npc;
    float vals[80];
    #pragma unroll
    for (int s = 0; s < 80; ++s) vals[s] = 0.f;
    for (int t = threadIdx.x; t < npc; t += 256) {
        int n = n0 + t;
        float qv[8], kv[8];
        #pragma unroll
        for (int i = 0; i < 8; ++i) qv[i] = qb[i * NPOS + n];
        #pragma unroll
        for (int j = 0; j < 8; ++j) kv[j] = kb[j * NPOS + n];
        #pragma unroll
        for (int i = 0; i < 8; ++i) {
            #pragma unroll
            for (int j = 0; j < 8; ++j)
                vals[i * 8 + j] = fmaf(qv[i], kv[j], vals[i * 8 + j]);
        }
        #pragma unroll
        for (int i = 0; i < 8; ++i) vals[64 + i] = fmaf(qv[i], qv[i], vals[64 + i]);
        #pragma unroll
        for (int j = 0; j < 8; ++j) vals[72 + j] = fmaf(kv[j], kv[j], vals[72 + j]);
    }
    __shared__ float red[4][80];
    const int lane = threadIdx.x & 63, wv = threadIdx.x >> 6;
    #pragma unroll
    for (int s = 0; s < 80; ++s) {
        float v = vals[s];
        #pragma unroll
        for (int off = 32; off > 0; off >>= 1)
            v += __shfl_xor(v, off, 64);
        if (lane == 0) red[wv][s] = v;
    }
    __syncthreads();
    if (threadIdx.x < 80)
        partial[((long long)bh * NCHUNK + chunk) * 80 + threadIdx.x] =
            red[0][threadIdx.x] + red[1][threadIdx.x] + red[2][threadIdx.x] + red[3][threadIdx.x];
}

// ---------------- K3b: deterministic chunk reduction ----------------
__global__ void k3b_reduce(const float* __restrict__ partial, float* __restrict__ gram) {
    int s = blockIdx.x * 256 + threadIdx.x;
    if (s >= 16 * 80) return;
    int bh = s / 80, slot = s % 80;
    float acc = 0.f;
    for (int c = 0; c < NCHUNK; ++c)
        acc += partial[((long long)bh * NCHUNK + c) * 80 + slot];
    gram[s] = acc;
}

// ---------------- K4: attn -> topk mask softmax -> combined P ----------------
__global__ void k4_combine(const float* __restrict__ gram, const float* __restrict__ temp,
                           const float* __restrict__ aw, float* __restrict__ P) {
    int t = threadIdx.x;               // one (b,h,i) row per thread; 128 threads
    if (t >= 128) return;
    int bh = t >> 3, i = t & 7;
    int h = bh & 7;
    const float* g = gram + bh * 80;
    float qn = fmaxf(sqrtf(g[64 + i]), 1e-12f);
    float tp = temp[h];
    float attn[8];
    #pragma unroll
    for (int j = 0; j < 8; ++j) {
        float kn = fmaxf(sqrtf(g[72 + j]), 1e-12f);
        attn[j] = g[i * 8 + j] / (qn * kn) * tp;
    }
    float awv[4];
    float am = -3.4e38f;
    for (int r = 0; r < 4; ++r) { awv[r] = aw[r]; am = fmaxf(am, awv[r]); }
    float asum = 0.f;
    for (int r = 0; r < 4; ++r) { awv[r] = expf(awv[r] - am); asum += awv[r]; }
    const int kvs[4] = {4, 5, 6, 6};   // int(8*ratio) for 0.5,0.67,0.75,0.8
    float Pacc[8];
    #pragma unroll
    for (int j = 0; j < 8; ++j) Pacc[j] = 0.f;
    for (int r = 0; r < 4; ++r) {
        float sw = awv[r] / asum;
        int kv = kvs[r];
        bool sel[8];
        #pragma unroll
        for (int j = 0; j < 8; ++j) sel[j] = false;
        for (int m = 0; m < kv; ++m) {     // exact top_k: ties -> smallest index
            int best = 0; float bv = -3.4e38f;
            for (int j = 0; j < 8; ++j)
                if (!sel[j] && attn[j] > bv) { bv = attn[j]; best = j; }
            sel[best] = true;
        }
        float mx = -3.4e38f;
        for (int j = 0; j < 8; ++j) if (sel[j]) mx = fmaxf(mx, attn[j]);
        float es = 0.f, e[8];
        for (int j = 0; j < 8; ++j) { e[j] = sel[j] ? expf(attn[j] - mx) : 0.f; es += e[j]; }
        for (int j = 0; j < 8; ++j) Pacc[j] += sw * e[j] / es;
    }
    for (int j = 0; j < 8; ++j) P[t * 8 + j] = Pacc[j];
}

// ---------------- K5: fused tail, wave-uniform channel mapping ----------------
// block = 64 positions x 64 channels; 4 waves; wave w owns out-channels
// [16w,16w+16), lane = position. Weight addresses are wave-uniform -> scalar
// loads; LDS reads are 1 x b32/lane per c (stride-1, conflict-free).
// As: v -> weighted -> enhanced -> fus (ping-pong); Xs holds residual x.
__global__ __launch_bounds__(256) void k5_tail(
        const float* __restrict__ qkv2, const float* __restrict__ x,
        const float* __restrict__ P,
        const float* __restrict__ Wrt, const float* __restrict__ br,
        const float* __restrict__ bn1g, const float* __restrict__ bn1b,
        const float* __restrict__ Wft, const float* __restrict__ bfu,
        const float* __restrict__ bn2g, const float* __restrict__ bn2b,
        const float* __restrict__ Wpt, const float* __restrict__ bp,
        float* __restrict__ out) {
    __shared__ __align__(16) float As[64 * 64];
    __shared__ __align__(16) float Xs[64 * 64];
    __shared__ float Pl[512];
    const int tid = threadIdx.x;
    const int lane = tid & 63;
    const int blk = blockIdx.x;
    const int b = blk >> 10;                 // 1024 blocks per batch
    const int n0 = (blk & 1023) << 6;
    const float* vg = qkv2 + ((long long)b * 192 + 128) * NPOS + n0;
    const float* xg = x + ((long long)b * 64) * NPOS + n0;
    #pragma unroll
    for (int k = 0; k < 4; ++k) {
        int idx = tid + k * 256;             // 1024 float4 tiles of [64ch][64pos]
        int ch = idx >> 4, p = (idx & 15) << 2;
        *(float4*)(As + ch * 64 + p) = *(const float4*)(vg + (long long)ch * NPOS + p);
        *(float4*)(Xs + ch * 64 + p) = *(const float4*)(xg + (long long)ch * NPOS + p);
    }
    Pl[tid] = P[b * 512 + tid];
    Pl[tid + 256] = P[b * 512 + 256 + tid];
    __syncthreads();

    const int wch0 = __builtin_amdgcn_readfirstlane((tid >> 6) << 4);  // SGPR
    const float invs = 1.0f / sqrtf(1.0f + 1e-5f);
    const float* wrp = Wrt + wch0;
    const float* wfp = Wft + wch0;
    const float* wpp = Wpt + wch0;

    // ---- stage 1: weighted = P @ v (wave reads/writes only its own 16 rows)
    float wacc[16];
    #pragma unroll
    for (int u = 0; u < 16; ++u) wacc[u] = 0.f;
    #pragma unroll
    for (int j = 0; j < 8; ++j) {
        const float v0 = As[(wch0 + j) * 64 + lane];
        const float v1 = As[(wch0 + 8 + j) * 64 + lane];
        #pragma unroll
        for (int u = 0; u < 8; ++u)
            wacc[u] = fmaf(Pl[wch0 * 8 + u * 8 + j], v0, wacc[u]);
        #pragma unroll
        for (int u = 0; u < 8; ++u)
            wacc[8 + u] = fmaf(Pl[wch0 * 8 + 64 + u * 8 + j], v1, wacc[8 + u]);
    }
    // in-wave LDS ordering makes this safe without a barrier (self rows only)
    #pragma unroll
    for (int u = 0; u < 16; ++u) As[(wch0 + u) * 64 + lane] = wacc[u];
    __syncthreads();

    // ---- recalib = sigmoid(bn1(Wr @ weighted)); enhanced = weighted * rec
    float a2[16];
    #pragma unroll
    for (int u = 0; u < 16; ++u) a2[u] = br[wch0 + u];
    for (int c = 0; c < 64; ++c) {
        const float bv = As[c * 64 + lane];
        #pragma unroll
        for (int u = 0; u < 16; ++u)
            a2[u] = fmaf(wrp[c * 64 + u], bv, a2[u]);
    }
    float enh[16];
    #pragma unroll
    for (int u = 0; u < 16; ++u) {
        const float s = bn1g[wch0 + u] * invs, tt = bn1b[wch0 + u];
        const float z = fmaf(a2[u], s, tt);
        enh[u] = wacc[u] / (1.f + expf(-z));
    }
    __syncthreads();                          // all recalib reads done
    #pragma unroll
    for (int u = 0; u < 16; ++u) As[(wch0 + u) * 64 + lane] = enh[u];
    __syncthreads();

    // ---- fus = bn2(Wf @ [enhanced; x])
    float f2[16];
    #pragma unroll
    for (int u = 0; u < 16; ++u) f2[u] = bfu[wch0 + u];
    for (int c = 0; c < 64; ++c) {
        const float av = As[c * 64 + lane];
        #pragma unroll
        for (int u = 0; u < 16; ++u)
            f2[u] = fmaf(wfp[c * 64 + u], av, f2[u]);
    }
    for (int c = 0; c < 64; ++c) {
        const float xv = Xs[c * 64 + lane];
        #pragma unroll
        for (int u = 0; u < 16; ++u)
            f2[u] = fmaf(wfp[(64 + c) * 64 + u], xv, f2[u]);
    }
    #pragma unroll
    for (int u = 0; u < 16; ++u) {
        const float s = bn2g[wch0 + u] * invs, tt = bn2b[wch0 + u];
        f2[u] = fmaf(f2[u], s, tt);
    }
    __syncthreads();                          // all fus reads done
    #pragma unroll
    for (int u = 0; u < 16; ++u) As[(wch0 + u) * 64 + lane] = f2[u];
    __syncthreads();

    // ---- proj -> out
    float p2[16];
    #pragma unroll
    for (int u = 0; u < 16; ++u) p2[u] = bp[wch0 + u];
    for (int c = 0; c < 64; ++c) {
        const float bv = As[c * 64 + lane];
        #pragma unroll
        for (int u = 0; u < 16; ++u)
            p2[u] = fmaf(wpp[c * 64 + u], bv, p2[u]);
    }
    #pragma unroll
    for (int u = 0; u < 16; ++u)
        out[((long long)b * 64 + wch0 + u) * NPOS + n0 + lane] = p2[u];
}

extern "C" void kernel_launch(void* const* d_in, const int* in_sizes, int n_in,
                              void* d_out, int out_size, void* d_ws, size_t ws_size,
                              hipStream_t stream) {
    (void)in_sizes; (void)n_in; (void)out_size; (void)ws_size;
    const float* x     = (const float*)d_in[0];
    const float* w_qkv = (const float*)d_in[1];
    const float* b_qkv = (const float*)d_in[2];
    const float* w_dw  = (const float*)d_in[3];
    const float* b_dw  = (const float*)d_in[4];
    const float* temp  = (const float*)d_in[5];
    const float* aw    = (const float*)d_in[6];
    const float* w_rec = (const float*)d_in[7];
    const float* b_rec = (const float*)d_in[8];
    const float* bn1g  = (const float*)d_in[9];
    const float* bn1b  = (const float*)d_in[10];
    const float* w_fus = (const float*)d_in[11];
    const float* b_fus = (const float*)d_in[12];
    const float* bn2g  = (const float*)d_in[13];
    const float* bn2b  = (const float*)d_in[14];
    const float* w_prj = (const float*)d_in[15];
    const float* b_prj = (const float*)d_in[16];
    float* out = (float*)d_out;
    float* ws  = (float*)d_ws;

    float* qkv  = ws;                       // 2*192*65536 = 25165824 floats
    float* qkv2 = qkv + 25165824;           // 25165824 floats
    float* part = qkv2 + 25165824;          // 16*128*80 = 163840
    float* gram = part + 163840;            // 1280
    float* P    = gram + 1280;              // 1024
    float* Wqt  = P + 1024;                 // 12288
    float* Wrt  = Wqt + 12288;              // 4096
    float* Wft  = Wrt + 4096;               // 8192
    float* Wpt  = Wft + 8192;               // 4096  (total ~202.1 MB)

    k0_transpose<<<112, 256, 0, stream>>>(w_qkv, w_rec, w_fus, w_prj, Wqt, Wrt, Wft, Wpt);
    k1_qkv<<<512, 256, 0, stream>>>(x, Wqt, b_qkv, qkv);
    k2_dw<<<6144, 256, 0, stream>>>(qkv, w_dw, b_dw, qkv2);
    k3_gram<<<16 * NCHUNK, 256, 0, stream>>>(qkv2, part);
    k3b_reduce<<<5, 256, 0, stream>>>(part, gram);
    k4_combine<<<1, 128, 0, stream>>>(gram, temp, aw, P);
    k5_tail<<<2048, 256, 0, stream>>>(qkv2, x, P, Wrt, b_rec, bn1g, bn1b,
                                      Wft, b_fus, bn2g, bn2b, Wpt, b_prj, out);
}

// Round 6
// 313.863 us; speedup vs baseline: 1.0195x; 1.0195x over previous
//
#include <hip/hip_runtime.h>
#include <math.h>

#define NPOS 65536          // D*H*W = 16*64*64
#define DD 16
#define HHH 64
#define WWW 64
#define NCHUNK 128

// ---------------- K0: transpose weights to [in][out] layouts ----------------
__global__ void k0_transpose(const float* __restrict__ Wq, const float* __restrict__ Wr,
                             const float* __restrict__ Wf, const float* __restrict__ Wp,
                             float* __restrict__ Wqt, float* __restrict__ Wrt,
                             float* __restrict__ Wft, float* __restrict__ Wpt) {
    int idx = blockIdx.x * 256 + threadIdx.x;
    if (idx < 192*64) { int oc = idx / 64, ic = idx % 64; Wqt[ic*192 + oc] = Wq[idx]; }
    int i2 = idx - 192*64;
    if (i2 >= 0 && i2 < 64*64) { int oc = i2 / 64, c = i2 % 64; Wrt[c*64 + oc] = Wr[i2]; }
    int i3 = i2 - 64*64;
    if (i3 >= 0 && i3 < 64*128) { int oc = i3 / 128, c = i3 % 128; Wft[c*64 + oc] = Wf[i3]; }
    int i4 = i3 - 64*128;
    if (i4 >= 0 && i4 < 64*64) { int oc = i4 / 64, c = i4 % 64; Wpt[c*64 + oc] = Wp[i4]; }
}

// ---------------- K1: pointwise qkv conv (192 out x 64 in) ----------------
__global__ __launch_bounds__(256) void k1_qkv(const float* __restrict__ x,
        const float* __restrict__ Wqt, const float* __restrict__ bq,
        float* __restrict__ qkv) {
    __shared__ float xs[64 * 256];
    const int tid = threadIdx.x;
    const int blk = blockIdx.x;
    const int b = blk >> 8;                 // 256 blocks per batch
    const int n0 = (blk & 255) << 8;
    const float* xb = x + ((long long)b * 64) * NPOS + n0;
    for (int ic = 0; ic < 64; ++ic)
        xs[ic * 256 + tid] = xb[(long long)ic * NPOS + tid];
    __syncthreads();
    float* outb = qkv + ((long long)b * 192) * NPOS + n0 + tid;
    for (int chunk = 0; chunk < 3; ++chunk) {
        float acc[64];
        #pragma unroll
        for (int o = 0; o < 64; ++o) acc[o] = bq[chunk * 64 + o];
        for (int ic = 0; ic < 64; ++ic) {
            float xv = xs[ic * 256 + tid];
            #pragma unroll
            for (int o = 0; o < 64; ++o)
                acc[o] = fmaf(Wqt[ic * 192 + chunk * 64 + o], xv, acc[o]);
        }
        #pragma unroll
        for (int o = 0; o < 64; ++o)
            outb[(long long)(chunk * 64 + o) * NPOS] = acc[o];
    }
}

// ---------------- K2: depthwise 3x3x3 conv via LDS stencil tile ----------------
__global__ __launch_bounds__(256) void k2_dw(const float* __restrict__ qkv,
        const float* __restrict__ Wd, const float* __restrict__ bd,
        float* __restrict__ qkv2) {
    __shared__ __align__(16) float tile[108 * 84];
    __shared__ float wsh[28];
    const int tid = threadIdx.x;
    const int bc  = blockIdx.x >> 4;        // 0..383 = b*192 + c
    const int sub = blockIdx.x & 15;
    const int d0  = (sub >> 2) << 2;        // 0,4,8,12
    const int h0  = (sub & 3) << 4;         // 0,16,32,48
    const int c   = bc % 192;

    if (tid < 27) wsh[tid] = Wd[c * 27 + tid];
    if (tid == 31) wsh[27] = bd[c];

    const float* in = qkv + (long long)bc * NPOS;
    for (int r = tid; r < 108; r += 256) {
        tile[r * 84 + 3]  = 0.f;
        tile[r * 84 + 68] = 0.f;
    }
    for (int i = tid; i < 1728; i += 256) {
        const int r = i >> 4, q = i & 15;
        const int dd = r / 18;              // 0..5
        const int hh = r - dd * 18;         // 0..17
        const int d = d0 + dd - 1;
        const int h = h0 + hh - 1;
        float4 v = make_float4(0.f, 0.f, 0.f, 0.f);
        if (d >= 0 && d < DD && h >= 0 && h < HHH)
            v = *(const float4*)(in + (d << 12) + (h << 6) + (q << 2));
        *(float4*)(tile + r * 84 + 4 + (q << 2)) = v;
    }
    __syncthreads();

    float wreg[27];
    #pragma unroll
    for (int s = 0; s < 27; ++s) wreg[s] = wsh[s];
    const float bias = wsh[27];

    const int wg  = tid & 7;
    const int w0  = wg << 3;                // 8 outputs along w
    const int rid = tid >> 3;               // 0..31
    const int oh  = rid & 15;               // 0..15
    const int od  = (rid >> 4) << 1;        // 0 or 2 (d-pair base)

    float acc0[8], acc1[8];
    #pragma unroll
    for (int j = 0; j < 8; ++j) { acc0[j] = bias; acc1[j] = bias; }

    #pragma unroll
    for (int kh = 0; kh < 3; ++kh) {
        #pragma unroll
        for (int dd = 0; dd < 4; ++dd) {
            const float* row = tile + ((od + dd) * 18 + oh + kh) * 84 + w0;
            const float4 q0 = *(const float4*)(row);
            const float4 q1 = *(const float4*)(row + 4);
            const float4 q2 = *(const float4*)(row + 8);
            const float4 q3 = *(const float4*)(row + 12);
            const float e0 = q0.w, e1 = q1.x, e2 = q1.y, e3 = q1.z, e4 = q1.w;
            const float e5 = q2.x, e6 = q2.y, e7 = q2.z, e8 = q2.w, e9 = q3.x;
            const float ee[10] = {e0,e1,e2,e3,e4,e5,e6,e7,e8,e9};
            if (dd < 3) {
                const float W0 = wreg[dd * 9 + kh * 3 + 0];
                const float W1 = wreg[dd * 9 + kh * 3 + 1];
                const float W2 = wreg[dd * 9 + kh * 3 + 2];
                #pragma unroll
                for (int j = 0; j < 8; ++j)
                    acc0[j] = fmaf(W0, ee[j], fmaf(W1, ee[j+1], fmaf(W2, ee[j+2], acc0[j])));
            }
            if (dd > 0) {
                const float W0 = wreg[(dd-1) * 9 + kh * 3 + 0];
                const float W1 = wreg[(dd-1) * 9 + kh * 3 + 1];
                const float W2 = wreg[(dd-1) * 9 + kh * 3 + 2];
                #pragma unroll
                for (int j = 0; j < 8; ++j)
                    acc1[j] = fmaf(W0, ee[j], fmaf(W1, ee[j+1], fmaf(W2, ee[j+2], acc1[j])));
            }
        }
    }
    float* outp = qkv2 + (long long)bc * NPOS + ((d0 + od) << 12) + ((h0 + oh) << 6) + w0;
    *(float4*)(outp)          = make_float4(acc0[0], acc0[1], acc0[2], acc0[3]);
    *(float4*)(outp + 4)      = make_float4(acc0[4], acc0[5], acc0[6], acc0[7]);
    *(float4*)(outp + 4096)     = make_float4(acc1[0], acc1[1], acc1[2], acc1[3]);
    *(float4*)(outp + 4096 + 4) = make_float4(acc1[4], acc1[5], acc1[6], acc1[7]);
}

// ---------------- K3: Gram partials: per (b,h,chunk) -> 64 qk + 8 qq + 8 kk ----------------
__global__ __launch_bounds__(256) void k3_gram(const float* __restrict__ qkv2,
                                               float* __restrict__ partial) {
    const int blk = blockIdx.x;
    const int chunk = blk & (NCHUNK - 1);
    const int bh = blk >> 7;                  // 0..15
    const int b = bh >> 3, h = bh & 7;
    const float* qb = qkv2 + ((long long)b * 192 + h * 8) * NPOS;
    const float* kb = qb + 64 * NPOS;
    const int npc = NPOS / NCHUNK;            // 512
    const int n0 = chunk * npc;
    float vals[80];
    #pragma unroll
    for (int s = 0; s < 80; ++s) vals[s] = 0.f;
    for (int t = threadIdx.x; t < npc; t += 256) {
        int n = n0 + t;
        float qv[8], kv[8];
        #pragma unroll
        for (int i = 0; i < 8; ++i) qv[i] = qb[i * NPOS + n];
        #pragma unroll
        for (int j = 0; j < 8; ++j) kv[j] = kb[j * NPOS + n];
        #pragma unroll
        for (int i = 0; i < 8; ++i) {
            #pragma unroll
            for (int j = 0; j < 8; ++j)
                vals[i * 8 + j] = fmaf(qv[i], kv[j], vals[i * 8 + j]);
        }
        #pragma unroll
        for (int i = 0; i < 8; ++i) vals[64 + i] = fmaf(qv[i], qv[i], vals[64 + i]);
        #pragma unroll
        for (int j = 0; j < 8; ++j) vals[72 + j] = fmaf(kv[j], kv[j], vals[72 + j]);
    }
    __shared__ float red[4][80];
    const int lane = threadIdx.x & 63, wv = threadIdx.x >> 6;
    #pragma unroll
    for (int s = 0; s < 80; ++s) {
        float v = vals[s];
        #pragma unroll
        for (int off = 32; off > 0; off >>= 1)
            v += __shfl_xor(v, off, 64);
        if (lane == 0) red[wv][s] = v;
    }
    __syncthreads();
    if (threadIdx.x < 80)
        partial[((long long)bh * NCHUNK + chunk) * 80 + threadIdx.x] =
            red[0][threadIdx.x] + red[1][threadIdx.x] + red[2][threadIdx.x] + red[3][threadIdx.x];
}

// ---------------- K3b: deterministic chunk reduction ----------------
__global__ void k3b_reduce(const float* __restrict__ partial, float* __restrict__ gram) {
    int s = blockIdx.x * 256 + threadIdx.x;
    if (s >= 16 * 80) return;
    int bh = s / 80, slot = s % 80;
    float acc = 0.f;
    for (int c = 0; c < NCHUNK; ++c)
        acc += partial[((long long)bh * NCHUNK + c) * 80 + slot];
    gram[s] = acc;
}

// ---------------- K4: attn -> topk mask softmax -> combined P ----------------
__global__ void k4_combine(const float* __restrict__ gram, const float* __restrict__ temp,
                           const float* __restrict__ aw, float* __restrict__ P) {
    int t = threadIdx.x;               // one (b,h,i) row per thread; 128 threads
    if (t >= 128) return;
    int bh = t >> 3, i = t & 7;
    int h = bh & 7;
    const float* g = gram + bh * 80;
    float qn = fmaxf(sqrtf(g[64 + i]), 1e-12f);
    float tp = temp[h];
    float attn[8];
    #pragma unroll
    for (int j = 0; j < 8; ++j) {
        float kn = fmaxf(sqrtf(g[72 + j]), 1e-12f);
        attn[j] = g[i * 8 + j] / (qn * kn) * tp;
    }
    float awv[4];
    float am = -3.4e38f;
    for (int r = 0; r < 4; ++r) { awv[r] = aw[r]; am = fmaxf(am, awv[r]); }
    float asum = 0.f;
    for (int r = 0; r < 4; ++r) { awv[r] = expf(awv[r] - am); asum += awv[r]; }
    const int kvs[4] = {4, 5, 6, 6};   // int(8*ratio) for 0.5,0.67,0.75,0.8
    float Pacc[8];
    #pragma unroll
    for (int j = 0; j < 8; ++j) Pacc[j] = 0.f;
    for (int r = 0; r < 4; ++r) {
        float sw = awv[r] / asum;
        int kv = kvs[r];
        bool sel[8];
        #pragma unroll
        for (int j = 0; j < 8; ++j) sel[j] = false;
        for (int m = 0; m < kv; ++m) {     // exact top_k: ties -> smallest index
            int best = 0; float bv = -3.4e38f;
            for (int j = 0; j < 8; ++j)
                if (!sel[j] && attn[j] > bv) { bv = attn[j]; best = j; }
            sel[best] = true;
        }
        float mx = -3.4e38f;
        for (int j = 0; j < 8; ++j) if (sel[j]) mx = fmaxf(mx, attn[j]);
        float es = 0.f, e[8];
        for (int j = 0; j < 8; ++j) { e[j] = sel[j] ? expf(attn[j] - mx) : 0.f; es += e[j]; }
        for (int j = 0; j < 8; ++j) Pacc[j] += sw * e[j] / es;
    }
    for (int j = 0; j < 8; ++j) P[t * 8 + j] = Pacc[j];
}

// ---------------- K5: fused tail, wave-uniform channels + chunked act reads ----
// block = 64 positions x 64 channels; 4 waves; wave w owns out-channels
// [16w,16w+16), lane = position. Weights -> scalar loads (SMEM). Activations
// are read from LDS in chunks of 8 into registers, so each lgkm wait covers
// 128 reg-only FMAs (avoids per-iteration SMEM/DS lgkmcnt(0) drains).
__global__ __launch_bounds__(256) void k5_tail(
        const float* __restrict__ qkv2, const float* __restrict__ x,
        const float* __restrict__ P,
        const float* __restrict__ Wrt, const float* __restrict__ br,
        const float* __restrict__ bn1g, const float* __restrict__ bn1b,
        const float* __restrict__ Wft, const float* __restrict__ bfu,
        const float* __restrict__ bn2g, const float* __restrict__ bn2b,
        const float* __restrict__ Wpt, const float* __restrict__ bp,
        float* __restrict__ out) {
    __shared__ __align__(16) float As[64 * 64];
    __shared__ __align__(16) float Xs[64 * 64];
    __shared__ float Pl[512];
    const int tid = threadIdx.x;
    const int lane = tid & 63;
    const int blk = blockIdx.x;
    const int b = blk >> 10;                 // 1024 blocks per batch
    const int n0 = (blk & 1023) << 6;
    const float* vg = qkv2 + ((long long)b * 192 + 128) * NPOS + n0;
    const float* xg = x + ((long long)b * 64) * NPOS + n0;
    #pragma unroll
    for (int k = 0; k < 4; ++k) {
        int idx = tid + k * 256;             // 1024 float4 tiles of [64ch][64pos]
        int ch = idx >> 4, p = (idx & 15) << 2;
        *(float4*)(As + ch * 64 + p) = *(const float4*)(vg + (long long)ch * NPOS + p);
        *(float4*)(Xs + ch * 64 + p) = *(const float4*)(xg + (long long)ch * NPOS + p);
    }
    Pl[tid] = P[b * 512 + tid];
    Pl[tid + 256] = P[b * 512 + 256 + tid];
    __syncthreads();

    const int wch0 = __builtin_amdgcn_readfirstlane((tid >> 6) << 4);  // SGPR
    const float invs = 1.0f / sqrtf(1.0f + 1e-5f);
    const float* wrp = Wrt + wch0;
    const float* wfp = Wft + wch0;
    const float* wpp = Wpt + wch0;

    // ---- stage 1: weighted = P @ v (wave reads/writes only its own 16 rows)
    float wacc[16];
    #pragma unroll
    for (int u = 0; u < 16; ++u) wacc[u] = 0.f;
    #pragma unroll
    for (int j = 0; j < 8; ++j) {
        const float v0 = As[(wch0 + j) * 64 + lane];
        const float v1 = As[(wch0 + 8 + j) * 64 + lane];
        #pragma unroll
        for (int u = 0; u < 8; ++u)
            wacc[u] = fmaf(Pl[wch0 * 8 + u * 8 + j], v0, wacc[u]);
        #pragma unroll
        for (int u = 0; u < 8; ++u)
            wacc[8 + u] = fmaf(Pl[wch0 * 8 + 64 + u * 8 + j], v1, wacc[8 + u]);
    }
    // in-wave LDS ordering makes this safe without a barrier (self rows only)
    #pragma unroll
    for (int u = 0; u < 16; ++u) As[(wch0 + u) * 64 + lane] = wacc[u];
    __syncthreads();

    // ---- recalib = sigmoid(bn1(Wr @ weighted)); enhanced = weighted * rec
    float a2[16];
    #pragma unroll
    for (int u = 0; u < 16; ++u) a2[u] = br[wch0 + u];
    for (int c0 = 0; c0 < 64; c0 += 8) {
        float a[8];
        #pragma unroll
        for (int k = 0; k < 8; ++k) a[k] = As[(c0 + k) * 64 + lane];
        #pragma unroll
        for (int k = 0; k < 8; ++k)
            #pragma unroll
            for (int u = 0; u < 16; ++u)
                a2[u] = fmaf(wrp[(c0 + k) * 64 + u], a[k], a2[u]);
    }
    float enh[16];
    #pragma unroll
    for (int u = 0; u < 16; ++u) {
        const float s = bn1g[wch0 + u] * invs, tt = bn1b[wch0 + u];
        const float z = fmaf(a2[u], s, tt);
        enh[u] = wacc[u] / (1.f + expf(-z));
    }
    __syncthreads();                          // all recalib reads done
    #pragma unroll
    for (int u = 0; u < 16; ++u) As[(wch0 + u) * 64 + lane] = enh[u];
    __syncthreads();

    // ---- fus = bn2(Wf @ [enhanced; x])
    float f2[16];
    #pragma unroll
    for (int u = 0; u < 16; ++u) f2[u] = bfu[wch0 + u];
    for (int c0 = 0; c0 < 64; c0 += 8) {
        float a[8];
        #pragma unroll
        for (int k = 0; k < 8; ++k) a[k] = As[(c0 + k) * 64 + lane];
        #pragma unroll
        for (int k = 0; k < 8; ++k)
            #pragma unroll
            for (int u = 0; u < 16; ++u)
                f2[u] = fmaf(wfp[(c0 + k) * 64 + u], a[k], f2[u]);
    }
    for (int c0 = 0; c0 < 64; c0 += 8) {
        float a[8];
        #pragma unroll
        for (int k = 0; k < 8; ++k) a[k] = Xs[(c0 + k) * 64 + lane];
        #pragma unroll
        for (int k = 0; k < 8; ++k)
            #pragma unroll
            for (int u = 0; u < 16; ++u)
                f2[u] = fmaf(wfp[(64 + c0 + k) * 64 + u], a[k], f2[u]);
    }
    #pragma unroll
    for (int u = 0; u < 16; ++u) {
        const float s = bn2g[wch0 + u] * invs, tt = bn2b[wch0 + u];
        f2[u] = fmaf(f2[u], s, tt);
    }
    __syncthreads();                          // all fus reads done
    #pragma unroll
    for (int u = 0; u < 16; ++u) As[(wch0 + u) * 64 + lane] = f2[u];
    __syncthreads();

    // ---- proj -> out
    float p2[16];
    #pragma unroll
    for (int u = 0; u < 16; ++u) p2[u] = bp[wch0 + u];
    for (int c0 = 0; c0 < 64; c0 += 8) {
        float a[8];
        #pragma unroll
        for (int k = 0; k < 8; ++k) a[k] = As[(c0 + k) * 64 + lane];
        #pragma unroll
        for (int k = 0; k < 8; ++k)
            #pragma unroll
            for (int u = 0; u < 16; ++u)
                p2[u] = fmaf(wpp[(c0 + k) * 64 + u], a[k], p2[u]);
    }
    #pragma unroll
    for (int u = 0; u < 16; ++u)
        out[((long long)b * 64 + wch0 + u) * NPOS + n0 + lane] = p2[u];
}

extern "C" void kernel_launch(void* const* d_in, const int* in_sizes, int n_in,
                              void* d_out, int out_size, void* d_ws, size_t ws_size,
                              hipStream_t stream) {
    (void)in_sizes; (void)n_in; (void)out_size; (void)ws_size;
    const float* x     = (const float*)d_in[0];
    const float* w_qkv = (const float*)d_in[1];
    const float* b_qkv = (const float*)d_in[2];
    const float* w_dw  = (const float*)d_in[3];
    const float* b_dw  = (const float*)d_in[4];
    const float* temp  = (const float*)d_in[5];
    const float* aw    = (const float*)d_in[6];
    const float* w_rec = (const float*)d_in[7];
    const float* b_rec = (const float*)d_in[8];
    const float* bn1g  = (const float*)d_in[9];
    const float* bn1b  = (const float*)d_in[10];
    const float* w_fus = (const float*)d_in[11];
    const float* b_fus = (const float*)d_in[12];
    const float* bn2g  = (const float*)d_in[13];
    const float* bn2b  = (const float*)d_in[14];
    const float* w_prj = (const float*)d_in[15];
    const float* b_prj = (const float*)d_in[16];
    float* out = (float*)d_out;
    float* ws  = (float*)d_ws;

    float* qkv  = ws;                       // 2*192*65536 = 25165824 floats
    float* qkv2 = qkv + 25165824;           // 25165824 floats
    float* part = qkv2 + 25165824;          // 16*128*80 = 163840
    float* gram = part + 163840;            // 1280
    float* P    = gram + 1280;              // 1024
    float* Wqt  = P + 1024;                 // 12288
    float* Wrt  = Wqt + 12288;              // 4096
    float* Wft  = Wrt + 4096;               // 8192
    float* Wpt  = Wft + 8192;               // 4096  (total ~202.1 MB)

    k0_transpose<<<112, 256, 0, stream>>>(w_qkv, w_rec, w_fus, w_prj, Wqt, Wrt, Wft, Wpt);
    k1_qkv<<<512, 256, 0, stream>>>(x, Wqt, b_qkv, qkv);
    k2_dw<<<6144, 256, 0, stream>>>(qkv, w_dw, b_dw, qkv2);
    k3_gram<<<16 * NCHUNK, 256, 0, stream>>>(qkv2, part);
    k3b_reduce<<<5, 256, 0, stream>>>(part, gram);
    k4_combine<<<1, 128, 0, stream>>>(gram, temp, aw, P);
    k5_tail<<<2048, 256, 0, stream>>>(qkv2, x, P, Wrt, b_rec, bn1g, bn1b,
                                      Wft, b_fus, bn2g, bn2b, Wpt, b_prj, out);
}

// Round 7
// 251.490 us; speedup vs baseline: 1.2724x; 1.2480x over previous
//
#include <hip/hip_runtime.h>
#include <math.h>

#define NPOS 65536          // D*H*W = 16*64*64
#define DD 16
#define HHH 64
#define WWW 64
#define NCHUNK 128

typedef __attribute__((ext_vector_type(8))) short bf16x8;   // 8 bf16 (4 VGPR)
typedef __attribute__((ext_vector_type(4))) float f32x4;

static __device__ __forceinline__ short f2bf(float f) {
    union { float f; unsigned u; } v; v.f = f;
    unsigned r = (v.u + 0x7FFFu + ((v.u >> 16) & 1u)) >> 16;
    return (short)r;
}

// ---------------- K0: Wqt transpose + MFMA A-frag weight prep (BN folded) ----
// A-frag layout (mfma_f32_16x16x32_bf16): lane l holds A[row=16m+(l&15)]
// [k=32t+(l>>4)*8+e], e=0..7; buffer index (((t*M4+m)*64)+l)*8+e.
__global__ void k0_prep(const float* __restrict__ Wq,
                        const float* __restrict__ Wr, const float* __restrict__ Wf,
                        const float* __restrict__ Wp,
                        const float* __restrict__ brec,
                        const float* __restrict__ bn1g, const float* __restrict__ bn1b,
                        const float* __restrict__ bfus,
                        const float* __restrict__ bn2g, const float* __restrict__ bn2b,
                        float* __restrict__ Wqt, short* __restrict__ WrA,
                        short* __restrict__ WfA, short* __restrict__ WpA,
                        float* __restrict__ bias1, float* __restrict__ bias2) {
    const float invs = 1.0f / sqrtf(1.0f + 1e-5f);
    int idx = blockIdx.x * 256 + threadIdx.x;
    if (idx < 12288) { int oc = idx / 64, ic = idx % 64; Wqt[ic*192 + oc] = Wq[idx]; return; }
    int i = idx - 12288;
    if (i < 4096) {      // WrA: 2 K-tiles x 4 M-tiles, bn1 scale folded per out-row
        int e = i & 7, l = (i >> 3) & 63, m = (i >> 9) & 3, t = (i >> 11) & 1;
        int out = 16*m + (l & 15), k = 32*t + ((l >> 4) << 3) + e;
        WrA[i] = f2bf(Wr[out*64 + k] * bn1g[out] * invs);
        return;
    }
    i -= 4096;
    if (i < 8192) {      // WfA: 4 K-tiles (enh 0..63, x 64..127), bn2 folded
        int e = i & 7, l = (i >> 3) & 63, m = (i >> 9) & 3, t = (i >> 11) & 3;
        int out = 16*m + (l & 15), k = 32*t + ((l >> 4) << 3) + e;
        WfA[i] = f2bf(Wf[out*128 + k] * bn2g[out] * invs);
        return;
    }
    i -= 8192;
    if (i < 4096) {      // WpA: 2 K-tiles, no BN
        int e = i & 7, l = (i >> 3) & 63, m = (i >> 9) & 3, t = (i >> 11) & 1;
        int out = 16*m + (l & 15), k = 32*t + ((l >> 4) << 3) + e;
        WpA[i] = f2bf(Wp[out*64 + k]);
        return;
    }
    i -= 4096;
    if (i < 64)       bias1[i]    = brec[i]    * bn1g[i]    * invs + bn1b[i];
    else if (i < 128) bias2[i-64] = bfus[i-64] * bn2g[i-64] * invs + bn2b[i-64];
}

// ---------------- K1: pointwise qkv conv (192 out x 64 in) ----------------
__global__ __launch_bounds__(256) void k1_qkv(const float* __restrict__ x,
        const float* __restrict__ Wqt, const float* __restrict__ bq,
        float* __restrict__ qkv) {
    __shared__ float xs[64 * 256];
    const int tid = threadIdx.x;
    const int blk = blockIdx.x;
    const int b = blk >> 8;                 // 256 blocks per batch
    const int n0 = (blk & 255) << 8;
    const float* xb = x + ((long long)b * 64) * NPOS + n0;
    for (int ic = 0; ic < 64; ++ic)
        xs[ic * 256 + tid] = xb[(long long)ic * NPOS + tid];
    __syncthreads();
    float* outb = qkv + ((long long)b * 192) * NPOS + n0 + tid;
    for (int chunk = 0; chunk < 3; ++chunk) {
        float acc[64];
        #pragma unroll
        for (int o = 0; o < 64; ++o) acc[o] = bq[chunk * 64 + o];
        for (int ic = 0; ic < 64; ++ic) {
            float xv = xs[ic * 256 + tid];
            #pragma unroll
            for (int o = 0; o < 64; ++o)
                acc[o] = fmaf(Wqt[ic * 192 + chunk * 64 + o], xv, acc[o]);
        }
        #pragma unroll
        for (int o = 0; o < 64; ++o)
            outb[(long long)(chunk * 64 + o) * NPOS] = acc[o];
    }
}

// ---------------- K2: depthwise 3x3x3 conv via LDS stencil tile ----------------
__global__ __launch_bounds__(256) void k2_dw(const float* __restrict__ qkv,
        const float* __restrict__ Wd, const float* __restrict__ bd,
        float* __restrict__ qkv2) {
    __shared__ __align__(16) float tile[108 * 84];
    __shared__ float wsh[28];
    const int tid = threadIdx.x;
    const int bc  = blockIdx.x >> 4;        // 0..383 = b*192 + c
    const int sub = blockIdx.x & 15;
    const int d0  = (sub >> 2) << 2;        // 0,4,8,12
    const int h0  = (sub & 3) << 4;         // 0,16,32,48
    const int c   = bc % 192;

    if (tid < 27) wsh[tid] = Wd[c * 27 + tid];
    if (tid == 31) wsh[27] = bd[c];

    const float* in = qkv + (long long)bc * NPOS;
    for (int r = tid; r < 108; r += 256) {
        tile[r * 84 + 3]  = 0.f;
        tile[r * 84 + 68] = 0.f;
    }
    for (int i = tid; i < 1728; i += 256) {
        const int r = i >> 4, q = i & 15;
        const int dd = r / 18;              // 0..5
        const int hh = r - dd * 18;         // 0..17
        const int d = d0 + dd - 1;
        const int h = h0 + hh - 1;
        float4 v = make_float4(0.f, 0.f, 0.f, 0.f);
        if (d >= 0 && d < DD && h >= 0 && h < HHH)
            v = *(const float4*)(in + (d << 12) + (h << 6) + (q << 2));
        *(float4*)(tile + r * 84 + 4 + (q << 2)) = v;
    }
    __syncthreads();

    float wreg[27];
    #pragma unroll
    for (int s = 0; s < 27; ++s) wreg[s] = wsh[s];
    const float bias = wsh[27];

    const int wg  = tid & 7;
    const int w0  = wg << 3;                // 8 outputs along w
    const int rid = tid >> 3;               // 0..31
    const int oh  = rid & 15;               // 0..15
    const int od  = (rid >> 4) << 1;        // 0 or 2 (d-pair base)

    float acc0[8], acc1[8];
    #pragma unroll
    for (int j = 0; j < 8; ++j) { acc0[j] = bias; acc1[j] = bias; }

    #pragma unroll
    for (int kh = 0; kh < 3; ++kh) {
        #pragma unroll
        for (int dd = 0; dd < 4; ++dd) {
            const float* row = tile + ((od + dd) * 18 + oh + kh) * 84 + w0;
            const float4 q0 = *(const float4*)(row);
            const float4 q1 = *(const float4*)(row + 4);
            const float4 q2 = *(const float4*)(row + 8);
            const float4 q3 = *(const float4*)(row + 12);
            const float e0 = q0.w, e1 = q1.x, e2 = q1.y, e3 = q1.z, e4 = q1.w;
            const float e5 = q2.x, e6 = q2.y, e7 = q2.z, e8 = q2.w, e9 = q3.x;
            const float ee[10] = {e0,e1,e2,e3,e4,e5,e6,e7,e8,e9};
            if (dd < 3) {
                const float W0 = wreg[dd * 9 + kh * 3 + 0];
                const float W1 = wreg[dd * 9 + kh * 3 + 1];
                const float W2 = wreg[dd * 9 + kh * 3 + 2];
                #pragma unroll
                for (int j = 0; j < 8; ++j)
                    acc0[j] = fmaf(W0, ee[j], fmaf(W1, ee[j+1], fmaf(W2, ee[j+2], acc0[j])));
            }
            if (dd > 0) {
                const float W0 = wreg[(dd-1) * 9 + kh * 3 + 0];
                const float W1 = wreg[(dd-1) * 9 + kh * 3 + 1];
                const float W2 = wreg[(dd-1) * 9 + kh * 3 + 2];
                #pragma unroll
                for (int j = 0; j < 8; ++j)
                    acc1[j] = fmaf(W0, ee[j], fmaf(W1, ee[j+1], fmaf(W2, ee[j+2], acc1[j])));
            }
        }
    }
    float* outp = qkv2 + (long long)bc * NPOS + ((d0 + od) << 12) + ((h0 + oh) << 6) + w0;
    *(float4*)(outp)          = make_float4(acc0[0], acc0[1], acc0[2], acc0[3]);
    *(float4*)(outp + 4)      = make_float4(acc0[4], acc0[5], acc0[6], acc0[7]);
    *(float4*)(outp + 4096)     = make_float4(acc1[0], acc1[1], acc1[2], acc1[3]);
    *(float4*)(outp + 4096 + 4) = make_float4(acc1[4], acc1[5], acc1[6], acc1[7]);
}

// ---------------- K3: Gram partials: per (b,h,chunk) -> 64 qk + 8 qq + 8 kk ----------------
__global__ __launch_bounds__(256) void k3_gram(const float* __restrict__ qkv2,
                                               float* __restrict__ partial) {
    const int blk = blockIdx.x;
    const int chunk = blk & (NCHUNK - 1);
    const int bh = blk >> 7;                  // 0..15
    const int b = bh >> 3, h = bh & 7;
    const float* qb = qkv2 + ((long long)b * 192 + h * 8) * NPOS;
    const float* kb = qb + 64 * NPOS;
    const int npc = NPOS / NCHUNK;            // 512
    const int n0 = chunk * npc;
    float vals[80];
    #pragma unroll
    for (int s = 0; s < 80; ++s) vals[s] = 0.f;
    for (int t = threadIdx.x; t < npc; t += 256) {
        int n = n0 + t;
        float qv[8], kv[8];
        #pragma unroll
        for (int i = 0; i < 8; ++i) qv[i] = qb[i * NPOS + n];
        #pragma unroll
        for (int j = 0; j < 8; ++j) kv[j] = kb[j * NPOS + n];
        #pragma unroll
        for (int i = 0; i < 8; ++i) {
            #pragma unroll
            for (int j = 0; j < 8; ++j)
                vals[i * 8 + j] = fmaf(qv[i], kv[j], vals[i * 8 + j]);
        }
        #pragma unroll
        for (int i = 0; i < 8; ++i) vals[64 + i] = fmaf(qv[i], qv[i], vals[64 + i]);
        #pragma unroll
        for (int j = 0; j < 8; ++j) vals[72 + j] = fmaf(kv[j], kv[j], vals[72 + j]);
    }
    __shared__ float red[4][80];
    const int lane = threadIdx.x & 63, wv = threadIdx.x >> 6;
    #pragma unroll
    for (int s = 0; s < 80; ++s) {
        float v = vals[s];
        #pragma unroll
        for (int off = 32; off > 0; off >>= 1)
            v += __shfl_xor(v, off, 64);
        if (lane == 0) red[wv][s] = v;
    }
    __syncthreads();
    if (threadIdx.x < 80)
        partial[((long long)bh * NCHUNK + chunk) * 80 + threadIdx.x] =
            red[0][threadIdx.x] + red[1][threadIdx.x] + red[2][threadIdx.x] + red[3][threadIdx.x];
}

// ---------------- K3b: deterministic chunk reduction ----------------
__global__ void k3b_reduce(const float* __restrict__ partial, float* __restrict__ gram) {
    int s = blockIdx.x * 256 + threadIdx.x;
    if (s >= 16 * 80) return;
    int bh = s / 80, slot = s % 80;
    float acc = 0.f;
    for (int c = 0; c < NCHUNK; ++c)
        acc += partial[((long long)bh * NCHUNK + c) * 80 + slot];
    gram[s] = acc;
}

// ---------------- K4: attn -> topk mask softmax -> combined P ----------------
__global__ void k4_combine(const float* __restrict__ gram, const float* __restrict__ temp,
                           const float* __restrict__ aw, float* __restrict__ P) {
    int t = threadIdx.x;               // one (b,h,i) row per thread; 128 threads
    if (t >= 128) return;
    int bh = t >> 3, i = t & 7;
    int h = bh & 7;
    const float* g = gram + bh * 80;
    float qn = fmaxf(sqrtf(g[64 + i]), 1e-12f);
    float tp = temp[h];
    float attn[8];
    #pragma unroll
    for (int j = 0; j < 8; ++j) {
        float kn = fmaxf(sqrtf(g[72 + j]), 1e-12f);
        attn[j] = g[i * 8 + j] / (qn * kn) * tp;
    }
    float awv[4];
    float am = -3.4e38f;
    for (int r = 0; r < 4; ++r) { awv[r] = aw[r]; am = fmaxf(am, awv[r]); }
    float asum = 0.f;
    for (int r = 0; r < 4; ++r) { awv[r] = expf(awv[r] - am); asum += awv[r]; }
    const int kvs[4] = {4, 5, 6, 6};   // int(8*ratio) for 0.5,0.67,0.75,0.8
    float Pacc[8];
    #pragma unroll
    for (int j = 0; j < 8; ++j) Pacc[j] = 0.f;
    for (int r = 0; r < 4; ++r) {
        float sw = awv[r] / asum;
        int kv = kvs[r];
        bool sel[8];
        #pragma unroll
        for (int j = 0; j < 8; ++j) sel[j] = false;
        for (int m = 0; m < kv; ++m) {     // exact top_k: ties -> smallest index
            int best = 0; float bv = -3.4e38f;
            for (int j = 0; j < 8; ++j)
                if (!sel[j] && attn[j] > bv) { bv = attn[j]; best = j; }
            sel[best] = true;
        }
        float mx = -3.4e38f;
        for (int j = 0; j < 8; ++j) if (sel[j]) mx = fmaxf(mx, attn[j]);
        float es = 0.f, e[8];
        for (int j = 0; j < 8; ++j) { e[j] = sel[j] ? expf(attn[j] - mx) : 0.f; es += e[j]; }
        for (int j = 0; j < 8; ++j) Pacc[j] += sw * e[j] / es;
    }
    for (int j = 0; j < 8; ++j) P[t * 8 + j] = Pacc[j];
}

// ---------------- K4b: expand P to block-diagonal 64x64 A-frags ----------------
__global__ void k4b_pfrag(const float* __restrict__ P, short* __restrict__ PA) {
    int idx = blockIdx.x * 256 + threadIdx.x;   // 8192 = 2b x 2t x 4m x 64l x 8e
    int e = idx & 7, l = (idx >> 3) & 63, m = (idx >> 9) & 3;
    int t = (idx >> 11) & 1, b = idx >> 12;
    int out = 16*m + (l & 15), k = 32*t + ((l >> 4) << 3) + e;
    float v = ((k >> 3) == (out >> 3)) ? P[(b * 64 + out) * 8 + (k & 7)] : 0.f;
    PA[idx] = f2bf(v);
}

// ---------------- K5: fused tail via bf16 MFMA ----------------
// block = 64 pos, 4 waves; wave wv owns pos cols [16wv,16wv+16).
// Each stage: B-frags from fp32 LDS tile (8 strided b32 + cvt), A-frags =
// pre-baked bf16 weights (BN folded), 8-16 MFMA, fp32 epilogue, write back.
__global__ __launch_bounds__(256) void k5_tail(
        const float* __restrict__ qkv2, const float* __restrict__ x,
        const short* __restrict__ PA, const short* __restrict__ WrA,
        const short* __restrict__ WfA, const short* __restrict__ WpA,
        const float* __restrict__ bias1, const float* __restrict__ bias2,
        const float* __restrict__ bp, float* __restrict__ out) {
    __shared__ __align__(16) float As[64 * 64];
    __shared__ __align__(16) float Xs[64 * 64];
    const int tid = threadIdx.x, lane = tid & 63, wv = tid >> 6;
    const int blk = blockIdx.x;
    const int b = blk >> 10, n0 = (blk & 1023) << 6;
    const float* vg = qkv2 + ((long long)b * 192 + 128) * NPOS + n0;
    const float* xg = x + ((long long)b * 64) * NPOS + n0;
    #pragma unroll
    for (int kk = 0; kk < 4; ++kk) {
        int idx = tid + kk * 256;            // [64ch][64pos] float4 tiles
        int ch = idx >> 4, p = (idx & 15) << 2;
        *(float4*)(As + ch * 64 + p) = *(const float4*)(vg + (long long)ch * NPOS + p);
        *(float4*)(Xs + ch * 64 + p) = *(const float4*)(xg + (long long)ch * NPOS + p);
    }
    bf16x8 pA[2][4];
    #pragma unroll
    for (int t = 0; t < 2; ++t)
        #pragma unroll
        for (int m = 0; m < 4; ++m)
            pA[t][m] = *(const bf16x8*)(PA + (((b * 2 + t) * 4 + m) * 64 + lane) * 8);
    const int bcol  = wv * 16 + (lane & 15);   // B col / D col
    const int bk    = (lane >> 4) << 3;        // B/A k-slice base
    const int drow0 = (lane >> 4) << 2;        // D row base within 16-tile
    __syncthreads();

    auto loadB = [&](const float* S, int kbase) {
        bf16x8 r;
        #pragma unroll
        for (int e = 0; e < 8; ++e) r[e] = f2bf(S[(kbase + bk + e) * 64 + bcol]);
        return r;
    };

    // ---- stage1: weighted = P_blockdiag @ v
    f32x4 Dw[4];
    {
        bf16x8 B0 = loadB(As, 0), B1 = loadB(As, 32);
        #pragma unroll
        for (int m = 0; m < 4; ++m) {
            f32x4 a = {0.f, 0.f, 0.f, 0.f};
            a = __builtin_amdgcn_mfma_f32_16x16x32_bf16(pA[0][m], B0, a, 0, 0, 0);
            a = __builtin_amdgcn_mfma_f32_16x16x32_bf16(pA[1][m], B1, a, 0, 0, 0);
            Dw[m] = a;
        }
    }
    __syncthreads();
    #pragma unroll
    for (int m = 0; m < 4; ++m)
        #pragma unroll
        for (int r = 0; r < 4; ++r)
            As[(16 * m + drow0 + r) * 64 + bcol] = Dw[m][r];
    __syncthreads();

    // ---- stage2: rec = sigmoid(Wr'@weighted + bias1); enh = weighted*rec
    float enh[4][4];
    {
        bf16x8 rA[2][4];
        #pragma unroll
        for (int t = 0; t < 2; ++t)
            #pragma unroll
            for (int m = 0; m < 4; ++m)
                rA[t][m] = *(const bf16x8*)(WrA + ((t * 4 + m) * 64 + lane) * 8);
        bf16x8 B0 = loadB(As, 0), B1 = loadB(As, 32);
        #pragma unroll
        for (int m = 0; m < 4; ++m) {
            f32x4 a = {0.f, 0.f, 0.f, 0.f};
            a = __builtin_amdgcn_mfma_f32_16x16x32_bf16(rA[0][m], B0, a, 0, 0, 0);
            a = __builtin_amdgcn_mfma_f32_16x16x32_bf16(rA[1][m], B1, a, 0, 0, 0);
            #pragma unroll
            for (int r = 0; r < 4; ++r) {
                float z = a[r] + bias1[16 * m + drow0 + r];
                enh[m][r] = Dw[m][r] / (1.f + expf(-z));
            }
        }
    }
    __syncthreads();
    #pragma unroll
    for (int m = 0; m < 4; ++m)
        #pragma unroll
        for (int r = 0; r < 4; ++r)
            As[(16 * m + drow0 + r) * 64 + bcol] = enh[m][r];
    __syncthreads();

    // ---- stage3: fusz = Wf'@[enh; x] + bias2
    f32x4 D3[4];
    {
        bf16x8 fA[4][4];
        #pragma unroll
        for (int t = 0; t < 4; ++t)
            #pragma unroll
            for (int m = 0; m < 4; ++m)
                fA[t][m] = *(const bf16x8*)(WfA + ((t * 4 + m) * 64 + lane) * 8);
        bf16x8 B0 = loadB(As, 0), B1 = loadB(As, 32);
        bf16x8 B2 = loadB(Xs, 0), B3 = loadB(Xs, 32);
        #pragma unroll
        for (int m = 0; m < 4; ++m) {
            f32x4 a = {0.f, 0.f, 0.f, 0.f};
            a = __builtin_amdgcn_mfma_f32_16x16x32_bf16(fA[0][m], B0, a, 0, 0, 0);
            a = __builtin_amdgcn_mfma_f32_16x16x32_bf16(fA[1][m], B1, a, 0, 0, 0);
            a = __builtin_amdgcn_mfma_f32_16x16x32_bf16(fA[2][m], B2, a, 0, 0, 0);
            a = __builtin_amdgcn_mfma_f32_16x16x32_bf16(fA[3][m], B3, a, 0, 0, 0);
            #pragma unroll
            for (int r = 0; r < 4; ++r) a[r] += bias2[16 * m + drow0 + r];
            D3[m] = a;
        }
    }
    __syncthreads();
    #pragma unroll
    for (int m = 0; m < 4; ++m)
        #pragma unroll
        for (int r = 0; r < 4; ++r)
            As[(16 * m + drow0 + r) * 64 + bcol] = D3[m][r];
    __syncthreads();

    // ---- stage4: out = Wp@fusz + bp
    f32x4 D4[4];
    {
        bf16x8 qA[2][4];
        #pragma unroll
        for (int t = 0; t < 2; ++t)
            #pragma unroll
            for (int m = 0; m < 4; ++m)
                qA[t][m] = *(const bf16x8*)(WpA + ((t * 4 + m) * 64 + lane) * 8);
        bf16x8 B0 = loadB(As, 0), B1 = loadB(As, 32);
        #pragma unroll
        for (int m = 0; m < 4; ++m) {
            f32x4 a = {0.f, 0.f, 0.f, 0.f};
            a = __builtin_amdgcn_mfma_f32_16x16x32_bf16(qA[0][m], B0, a, 0, 0, 0);
            a = __builtin_amdgcn_mfma_f32_16x16x32_bf16(qA[1][m], B1, a, 0, 0, 0);
            #pragma unroll
            for (int r = 0; r < 4; ++r) a[r] += bp[16 * m + drow0 + r];
            D4[m] = a;
        }
    }
    __syncthreads();
    #pragma unroll
    for (int m = 0; m < 4; ++m)
        #pragma unroll
        for (int r = 0; r < 4; ++r)
            As[(16 * m + drow0 + r) * 64 + bcol] = D4[m][r];
    __syncthreads();
    // coalesced store: thread -> (row = tid>>2, 16 pos)
    const int row = tid >> 2, q = tid & 3;
    #pragma unroll
    for (int j = 0; j < 4; ++j) {
        int p = q * 4 + j * 16;
        *(float4*)(out + ((long long)b * 64 + row) * NPOS + n0 + p) =
            *(const float4*)(As + row * 64 + p);
    }
}

extern "C" void kernel_launch(void* const* d_in, const int* in_sizes, int n_in,
                              void* d_out, int out_size, void* d_ws, size_t ws_size,
                              hipStream_t stream) {
    (void)in_sizes; (void)n_in; (void)out_size; (void)ws_size;
    const float* x     = (const float*)d_in[0];
    const float* w_qkv = (const float*)d_in[1];
    const float* b_qkv = (const float*)d_in[2];
    const float* w_dw  = (const float*)d_in[3];
    const float* b_dw  = (const float*)d_in[4];
    const float* temp  = (const float*)d_in[5];
    const float* aw    = (const float*)d_in[6];
    const float* w_rec = (const float*)d_in[7];
    const float* b_rec = (const float*)d_in[8];
    const float* bn1g  = (const float*)d_in[9];
    const float* bn1b  = (const float*)d_in[10];
    const float* w_fus = (const float*)d_in[11];
    const float* b_fus = (const float*)d_in[12];
    const float* bn2g  = (const float*)d_in[13];
    const float* bn2b  = (const float*)d_in[14];
    const float* w_prj = (const float*)d_in[15];
    const float* b_prj = (const float*)d_in[16];
    float* out = (float*)d_out;
    float* ws  = (float*)d_ws;

    float* qkv  = ws;                       // 2*192*65536 = 25165824 floats
    float* qkv2 = qkv + 25165824;           // 25165824 floats
    float* part = qkv2 + 25165824;          // 16*128*80 = 163840
    float* gram = part + 163840;            // 1280
    float* P    = gram + 1280;              // 1024
    float* Wqt  = P + 1024;                 // 12288
    float* bias1 = Wqt + 12288;             // 64
    float* bias2 = bias1 + 64;              // 64
    short* WrA  = (short*)(bias2 + 64);     // 4096 shorts (16B-aligned)
    short* WfA  = WrA + 4096;               // 8192 shorts
    short* WpA  = WfA + 8192;               // 4096 shorts
    short* PAb  = WpA + 4096;               // 8192 shorts

    k0_prep<<<113, 256, 0, stream>>>(w_qkv, w_rec, w_fus, w_prj, b_rec, bn1g, bn1b,
                                     b_fus, bn2g, bn2b, Wqt, WrA, WfA, WpA, bias1, bias2);
    k1_qkv<<<512, 256, 0, stream>>>(x, Wqt, b_qkv, qkv);
    k2_dw<<<6144, 256, 0, stream>>>(qkv, w_dw, b_dw, qkv2);
    k3_gram<<<16 * NCHUNK, 256, 0, stream>>>(qkv2, part);
    k3b_reduce<<<5, 256, 0, stream>>>(part, gram);
    k4_combine<<<1, 128, 0, stream>>>(gram, temp, aw, P);
    k4b_pfrag<<<32, 256, 0, stream>>>(P, PAb);
    k5_tail<<<2048, 256, 0, stream>>>(qkv2, x, PAb, WrA, WfA, WpA,
                                      bias1, bias2, b_prj, out);
}

// Round 8
// 200.874 us; speedup vs baseline: 1.5930x; 1.2520x over previous
//
#include <hip/hip_runtime.h>
#include <math.h>

#define NPOS 65536          // D*H*W = 16*64*64
#define DD 16
#define HHH 64
#define WWW 64
#define NCHUNK 128

typedef __attribute__((ext_vector_type(8))) short bf16x8;   // 8 bf16 (4 VGPR)
typedef __attribute__((ext_vector_type(4))) float f32x4;

static __device__ __forceinline__ short f2bf(float f) {
    union { float f; unsigned u; } v; v.f = f;
    unsigned r = (v.u + 0x7FFFu + ((v.u >> 16) & 1u)) >> 16;
    return (short)r;
}

// ---------------- K0: MFMA A-frag weight prep (BN folded) ----------------
// A-frag layout (mfma_f32_16x16x32_bf16): lane l holds A[row=16m+(l&15)]
// [k=32t+(l>>4)*8+e], e=0..7.
__global__ void k0_prep(const float* __restrict__ Wq,
                        const float* __restrict__ Wr, const float* __restrict__ Wf,
                        const float* __restrict__ Wp,
                        const float* __restrict__ brec,
                        const float* __restrict__ bn1g, const float* __restrict__ bn1b,
                        const float* __restrict__ bfus,
                        const float* __restrict__ bn2g, const float* __restrict__ bn2b,
                        short* __restrict__ WqA, short* __restrict__ WrA,
                        short* __restrict__ WfA, short* __restrict__ WpA,
                        float* __restrict__ bias1, float* __restrict__ bias2) {
    const float invs = 1.0f / sqrtf(1.0f + 1e-5f);
    int idx = blockIdx.x * 256 + threadIdx.x;
    if (idx < 12288) {   // WqA: 3 chunks x 2 K-tiles x 4 M-tiles
        int e = idx & 7, l = (idx >> 3) & 63, m = (idx >> 9) & 3;
        int t = (idx >> 11) & 1, c = idx >> 12;
        int out = c*64 + 16*m + (l & 15), k = 32*t + ((l >> 4) << 3) + e;
        WqA[idx] = f2bf(Wq[out*64 + k]);
        return;
    }
    int i = idx - 12288;
    if (i < 4096) {      // WrA: 2 K-tiles x 4 M-tiles, bn1 scale folded per out-row
        int e = i & 7, l = (i >> 3) & 63, m = (i >> 9) & 3, t = (i >> 11) & 1;
        int out = 16*m + (l & 15), k = 32*t + ((l >> 4) << 3) + e;
        WrA[i] = f2bf(Wr[out*64 + k] * bn1g[out] * invs);
        return;
    }
    i -= 4096;
    if (i < 8192) {      // WfA: 4 K-tiles (enh 0..63, x 64..127), bn2 folded
        int e = i & 7, l = (i >> 3) & 63, m = (i >> 9) & 3, t = (i >> 11) & 3;
        int out = 16*m + (l & 15), k = 32*t + ((l >> 4) << 3) + e;
        WfA[i] = f2bf(Wf[out*128 + k] * bn2g[out] * invs);
        return;
    }
    i -= 8192;
    if (i < 4096) {      // WpA: 2 K-tiles, no BN
        int e = i & 7, l = (i >> 3) & 63, m = (i >> 9) & 3, t = (i >> 11) & 1;
        int out = 16*m + (l & 15), k = 32*t + ((l >> 4) << 3) + e;
        WpA[i] = f2bf(Wp[out*64 + k]);
        return;
    }
    i -= 4096;
    if (i < 64)       bias1[i]    = brec[i]    * bn1g[i]    * invs + bn1b[i];
    else if (i < 128) bias2[i-64] = bfus[i-64] * bn2g[i-64] * invs + bn2b[i-64];
}

// ---------------- K1: pointwise qkv conv via bf16 MFMA ----------------
// block = 64 pos, 4 waves; wave wv owns pos cols [16wv,16wv+16).
// 3 chunks of 64 output rows; A = pre-baked WqA (L1-resident), B = x tile.
__global__ __launch_bounds__(256) void k1_qkv(const float* __restrict__ x,
        const short* __restrict__ WqA, const float* __restrict__ bq,
        float* __restrict__ qkv) {
    __shared__ __align__(16) float Xs[64 * 64];
    __shared__ __align__(16) float As[64 * 64];
    const int tid = threadIdx.x, lane = tid & 63, wv = tid >> 6;
    const int blk = blockIdx.x;
    const int b = blk >> 10, n0 = (blk & 1023) << 6;
    const float* xg = x + ((long long)b * 64) * NPOS + n0;
    #pragma unroll
    for (int kk = 0; kk < 4; ++kk) {
        int idx = tid + kk * 256;            // [64ch][64pos] float4 tiles
        int ch = idx >> 4, p = (idx & 15) << 2;
        *(float4*)(Xs + ch * 64 + p) = *(const float4*)(xg + (long long)ch * NPOS + p);
    }
    const int bcol  = wv * 16 + (lane & 15);
    const int bk    = (lane >> 4) << 3;
    const int drow0 = (lane >> 4) << 2;
    __syncthreads();

    bf16x8 B0, B1;
    #pragma unroll
    for (int e = 0; e < 8; ++e) B0[e] = f2bf(Xs[(bk + e) * 64 + bcol]);
    #pragma unroll
    for (int e = 0; e < 8; ++e) B1[e] = f2bf(Xs[(32 + bk + e) * 64 + bcol]);

    #pragma unroll
    for (int c = 0; c < 3; ++c) {
        f32x4 D[4];
        #pragma unroll
        for (int m = 0; m < 4; ++m) {
            bf16x8 A0 = *(const bf16x8*)(WqA + (((c * 2 + 0) * 4 + m) * 64 + lane) * 8);
            bf16x8 A1 = *(const bf16x8*)(WqA + (((c * 2 + 1) * 4 + m) * 64 + lane) * 8);
            f32x4 a = {0.f, 0.f, 0.f, 0.f};
            a = __builtin_amdgcn_mfma_f32_16x16x32_bf16(A0, B0, a, 0, 0, 0);
            a = __builtin_amdgcn_mfma_f32_16x16x32_bf16(A1, B1, a, 0, 0, 0);
            float4 bb = *(const float4*)(bq + c * 64 + 16 * m + drow0);
            a[0] += bb.x; a[1] += bb.y; a[2] += bb.z; a[3] += bb.w;
            D[m] = a;
        }
        if (c) __syncthreads();              // As consumed by previous chunk's store
        #pragma unroll
        for (int m = 0; m < 4; ++m)
            #pragma unroll
            for (int r = 0; r < 4; ++r)
                As[(16 * m + drow0 + r) * 64 + bcol] = D[m][r];
        __syncthreads();
        const int row = tid >> 2, q = tid & 3;
        #pragma unroll
        for (int j = 0; j < 4; ++j) {
            int p = q * 4 + j * 16;
            *(float4*)(qkv + ((long long)b * 192 + c * 64 + row) * NPOS + n0 + p) =
                *(const float4*)(As + row * 64 + p);
        }
    }
}

// ---------------- K2: depthwise 3x3x3 conv via LDS stencil tile ----------------
__global__ __launch_bounds__(256) void k2_dw(const float* __restrict__ qkv,
        const float* __restrict__ Wd, const float* __restrict__ bd,
        float* __restrict__ qkv2) {
    __shared__ __align__(16) float tile[108 * 84];
    __shared__ float wsh[28];
    const int tid = threadIdx.x;
    const int bc  = blockIdx.x >> 4;        // 0..383 = b*192 + c
    const int sub = blockIdx.x & 15;
    const int d0  = (sub >> 2) << 2;        // 0,4,8,12
    const int h0  = (sub & 3) << 4;         // 0,16,32,48
    const int c   = bc % 192;

    if (tid < 27) wsh[tid] = Wd[c * 27 + tid];
    if (tid == 31) wsh[27] = bd[c];

    const float* in = qkv + (long long)bc * NPOS;
    for (int r = tid; r < 108; r += 256) {
        tile[r * 84 + 3]  = 0.f;
        tile[r * 84 + 68] = 0.f;
    }
    for (int i = tid; i < 1728; i += 256) {
        const int r = i >> 4, q = i & 15;
        const int dd = r / 18;              // 0..5
        const int hh = r - dd * 18;         // 0..17
        const int d = d0 + dd - 1;
        const int h = h0 + hh - 1;
        float4 v = make_float4(0.f, 0.f, 0.f, 0.f);
        if (d >= 0 && d < DD && h >= 0 && h < HHH)
            v = *(const float4*)(in + (d << 12) + (h << 6) + (q << 2));
        *(float4*)(tile + r * 84 + 4 + (q << 2)) = v;
    }
    __syncthreads();

    float wreg[27];
    #pragma unroll
    for (int s = 0; s < 27; ++s) wreg[s] = wsh[s];
    const float bias = wsh[27];

    const int wg  = tid & 7;
    const int w0  = wg << 3;                // 8 outputs along w
    const int rid = tid >> 3;               // 0..31
    const int oh  = rid & 15;               // 0..15
    const int od  = (rid >> 4) << 1;        // 0 or 2 (d-pair base)

    float acc0[8], acc1[8];
    #pragma unroll
    for (int j = 0; j < 8; ++j) { acc0[j] = bias; acc1[j] = bias; }

    #pragma unroll
    for (int kh = 0; kh < 3; ++kh) {
        #pragma unroll
        for (int dd = 0; dd < 4; ++dd) {
            const float* row = tile + ((od + dd) * 18 + oh + kh) * 84 + w0;
            const float4 q0 = *(const float4*)(row);
            const float4 q1 = *(const float4*)(row + 4);
            const float4 q2 = *(const float4*)(row + 8);
            const float4 q3 = *(const float4*)(row + 12);
            const float e0 = q0.w, e1 = q1.x, e2 = q1.y, e3 = q1.z, e4 = q1.w;
            const float e5 = q2.x, e6 = q2.y, e7 = q2.z, e8 = q2.w, e9 = q3.x;
            const float ee[10] = {e0,e1,e2,e3,e4,e5,e6,e7,e8,e9};
            if (dd < 3) {
                const float W0 = wreg[dd * 9 + kh * 3 + 0];
                const float W1 = wreg[dd * 9 + kh * 3 + 1];
                const float W2 = wreg[dd * 9 + kh * 3 + 2];
                #pragma unroll
                for (int j = 0; j < 8; ++j)
                    acc0[j] = fmaf(W0, ee[j], fmaf(W1, ee[j+1], fmaf(W2, ee[j+2], acc0[j])));
            }
            if (dd > 0) {
                const float W0 = wreg[(dd-1) * 9 + kh * 3 + 0];
                const float W1 = wreg[(dd-1) * 9 + kh * 3 + 1];
                const float W2 = wreg[(dd-1) * 9 + kh * 3 + 2];
                #pragma unroll
                for (int j = 0; j < 8; ++j)
                    acc1[j] = fmaf(W0, ee[j], fmaf(W1, ee[j+1], fmaf(W2, ee[j+2], acc1[j])));
            }
        }
    }
    float* outp = qkv2 + (long long)bc * NPOS + ((d0 + od) << 12) + ((h0 + oh) << 6) + w0;
    *(float4*)(outp)          = make_float4(acc0[0], acc0[1], acc0[2], acc0[3]);
    *(float4*)(outp + 4)      = make_float4(acc0[4], acc0[5], acc0[6], acc0[7]);
    *(float4*)(outp + 4096)     = make_float4(acc1[0], acc1[1], acc1[2], acc1[3]);
    *(float4*)(outp + 4096 + 4) = make_float4(acc1[4], acc1[5], acc1[6], acc1[7]);
}

// ---------------- K3: Gram partials: per (b,h,chunk) -> 64 qk + 8 qq + 8 kk ----------------
__global__ __launch_bounds__(256) void k3_gram(const float* __restrict__ qkv2,
                                               float* __restrict__ partial) {
    const int blk = blockIdx.x;
    const int chunk = blk & (NCHUNK - 1);
    const int bh = blk >> 7;                  // 0..15
    const int b = bh >> 3, h = bh & 7;
    const float* qb = qkv2 + ((long long)b * 192 + h * 8) * NPOS;
    const float* kb = qb + 64 * NPOS;
    const int npc = NPOS / NCHUNK;            // 512
    const int n0 = chunk * npc;
    float vals[80];
    #pragma unroll
    for (int s = 0; s < 80; ++s) vals[s] = 0.f;
    for (int t = threadIdx.x; t < npc; t += 256) {
        int n = n0 + t;
        float qv[8], kv[8];
        #pragma unroll
        for (int i = 0; i < 8; ++i) qv[i] = qb[i * NPOS + n];
        #pragma unroll
        for (int j = 0; j < 8; ++j) kv[j] = kb[j * NPOS + n];
        #pragma unroll
        for (int i = 0; i < 8; ++i) {
            #pragma unroll
            for (int j = 0; j < 8; ++j)
                vals[i * 8 + j] = fmaf(qv[i], kv[j], vals[i * 8 + j]);
        }
        #pragma unroll
        for (int i = 0; i < 8; ++i) vals[64 + i] = fmaf(qv[i], qv[i], vals[64 + i]);
        #pragma unroll
        for (int j = 0; j < 8; ++j) vals[72 + j] = fmaf(kv[j], kv[j], vals[72 + j]);
    }
    __shared__ float red[4][80];
    const int lane = threadIdx.x & 63, wv = threadIdx.x >> 6;
    #pragma unroll
    for (int s = 0; s < 80; ++s) {
        float v = vals[s];
        #pragma unroll
        for (int off = 32; off > 0; off >>= 1)
            v += __shfl_xor(v, off, 64);
        if (lane == 0) red[wv][s] = v;
    }
    __syncthreads();
    if (threadIdx.x < 80)
        partial[((long long)bh * NCHUNK + chunk) * 80 + threadIdx.x] =
            red[0][threadIdx.x] + red[1][threadIdx.x] + red[2][threadIdx.x] + red[3][threadIdx.x];
}

// ---------------- K3b: deterministic chunk reduction ----------------
__global__ void k3b_reduce(const float* __restrict__ partial, float* __restrict__ gram) {
    int s = blockIdx.x * 256 + threadIdx.x;
    if (s >= 16 * 80) return;
    int bh = s / 80, slot = s % 80;
    float acc = 0.f;
    for (int c = 0; c < NCHUNK; ++c)
        acc += partial[((long long)bh * NCHUNK + c) * 80 + slot];
    gram[s] = acc;
}

// ---------------- K4: attn -> topk mask softmax -> combined P ----------------
__global__ void k4_combine(const float* __restrict__ gram, const float* __restrict__ temp,
                           const float* __restrict__ aw, float* __restrict__ P) {
    int t = threadIdx.x;               // one (b,h,i) row per thread; 128 threads
    if (t >= 128) return;
    int bh = t >> 3, i = t & 7;
    int h = bh & 7;
    const float* g = gram + bh * 80;
    float qn = fmaxf(sqrtf(g[64 + i]), 1e-12f);
    float tp = temp[h];
    float attn[8];
    #pragma unroll
    for (int j = 0; j < 8; ++j) {
        float kn = fmaxf(sqrtf(g[72 + j]), 1e-12f);
        attn[j] = g[i * 8 + j] / (qn * kn) * tp;
    }
    float awv[4];
    float am = -3.4e38f;
    for (int r = 0; r < 4; ++r) { awv[r] = aw[r]; am = fmaxf(am, awv[r]); }
    float asum = 0.f;
    for (int r = 0; r < 4; ++r) { awv[r] = expf(awv[r] - am); asum += awv[r]; }
    const int kvs[4] = {4, 5, 6, 6};   // int(8*ratio) for 0.5,0.67,0.75,0.8
    float Pacc[8];
    #pragma unroll
    for (int j = 0; j < 8; ++j) Pacc[j] = 0.f;
    for (int r = 0; r < 4; ++r) {
        float sw = awv[r] / asum;
        int kv = kvs[r];
        bool sel[8];
        #pragma unroll
        for (int j = 0; j < 8; ++j) sel[j] = false;
        for (int m = 0; m < kv; ++m) {     // exact top_k: ties -> smallest index
            int best = 0; float bv = -3.4e38f;
            for (int j = 0; j < 8; ++j)
                if (!sel[j] && attn[j] > bv) { bv = attn[j]; best = j; }
            sel[best] = true;
        }
        float mx = -3.4e38f;
        for (int j = 0; j < 8; ++j) if (sel[j]) mx = fmaxf(mx, attn[j]);
        float es = 0.f, e[8];
        for (int j = 0; j < 8; ++j) { e[j] = sel[j] ? expf(attn[j] - mx) : 0.f; es += e[j]; }
        for (int j = 0; j < 8; ++j) Pacc[j] += sw * e[j] / es;
    }
    for (int j = 0; j < 8; ++j) P[t * 8 + j] = Pacc[j];
}

// ---------------- K4b: expand P to block-diagonal 64x64 A-frags ----------------
__global__ void k4b_pfrag(const float* __restrict__ P, short* __restrict__ PA) {
    int idx = blockIdx.x * 256 + threadIdx.x;   // 8192 = 2b x 2t x 4m x 64l x 8e
    int e = idx & 7, l = (idx >> 3) & 63, m = (idx >> 9) & 3;
    int t = (idx >> 11) & 1, b = idx >> 12;
    int out = 16*m + (l & 15), k = 32*t + ((l >> 4) << 3) + e;
    float v = ((k >> 3) == (out >> 3)) ? P[(b * 64 + out) * 8 + (k & 7)] : 0.f;
    PA[idx] = f2bf(v);
}

// ---------------- K5: fused tail via bf16 MFMA ----------------
__global__ __launch_bounds__(256) void k5_tail(
        const float* __restrict__ qkv2, const float* __restrict__ x,
        const short* __restrict__ PA, const short* __restrict__ WrA,
        const short* __restrict__ WfA, const short* __restrict__ WpA,
        const float* __restrict__ bias1, const float* __restrict__ bias2,
        const float* __restrict__ bp, float* __restrict__ out) {
    __shared__ __align__(16) float As[64 * 64];
    __shared__ __align__(16) float Xs[64 * 64];
    const int tid = threadIdx.x, lane = tid & 63, wv = tid >> 6;
    const int blk = blockIdx.x;
    const int b = blk >> 10, n0 = (blk & 1023) << 6;
    const float* vg = qkv2 + ((long long)b * 192 + 128) * NPOS + n0;
    const float* xg = x + ((long long)b * 64) * NPOS + n0;
    #pragma unroll
    for (int kk = 0; kk < 4; ++kk) {
        int idx = tid + kk * 256;            // [64ch][64pos] float4 tiles
        int ch = idx >> 4, p = (idx & 15) << 2;
        *(float4*)(As + ch * 64 + p) = *(const float4*)(vg + (long long)ch * NPOS + p);
        *(float4*)(Xs + ch * 64 + p) = *(const float4*)(xg + (long long)ch * NPOS + p);
    }
    bf16x8 pA[2][4];
    #pragma unroll
    for (int t = 0; t < 2; ++t)
        #pragma unroll
        for (int m = 0; m < 4; ++m)
            pA[t][m] = *(const bf16x8*)(PA + (((b * 2 + t) * 4 + m) * 64 + lane) * 8);
    const int bcol  = wv * 16 + (lane & 15);   // B col / D col
    const int bk    = (lane >> 4) << 3;        // B/A k-slice base
    const int drow0 = (lane >> 4) << 2;        // D row base within 16-tile
    __syncthreads();

    auto loadB = [&](const float* S, int kbase) {
        bf16x8 r;
        #pragma unroll
        for (int e = 0; e < 8; ++e) r[e] = f2bf(S[(kbase + bk + e) * 64 + bcol]);
        return r;
    };

    // ---- stage1: weighted = P_blockdiag @ v
    f32x4 Dw[4];
    {
        bf16x8 B0 = loadB(As, 0), B1 = loadB(As, 32);
        #pragma unroll
        for (int m = 0; m < 4; ++m) {
            f32x4 a = {0.f, 0.f, 0.f, 0.f};
            a = __builtin_amdgcn_mfma_f32_16x16x32_bf16(pA[0][m], B0, a, 0, 0, 0);
            a = __builtin_amdgcn_mfma_f32_16x16x32_bf16(pA[1][m], B1, a, 0, 0, 0);
            Dw[m] = a;
        }
    }
    __syncthreads();
    #pragma unroll
    for (int m = 0; m < 4; ++m)
        #pragma unroll
        for (int r = 0; r < 4; ++r)
            As[(16 * m + drow0 + r) * 64 + bcol] = Dw[m][r];
    __syncthreads();

    // ---- stage2: rec = sigmoid(Wr'@weighted + bias1); enh = weighted*rec
    float enh[4][4];
    {
        bf16x8 rA[2][4];
        #pragma unroll
        for (int t = 0; t < 2; ++t)
            #pragma unroll
            for (int m = 0; m < 4; ++m)
                rA[t][m] = *(const bf16x8*)(WrA + ((t * 4 + m) * 64 + lane) * 8);
        bf16x8 B0 = loadB(As, 0), B1 = loadB(As, 32);
        #pragma unroll
        for (int m = 0; m < 4; ++m) {
            f32x4 a = {0.f, 0.f, 0.f, 0.f};
            a = __builtin_amdgcn_mfma_f32_16x16x32_bf16(rA[0][m], B0, a, 0, 0, 0);
            a = __builtin_amdgcn_mfma_f32_16x16x32_bf16(rA[1][m], B1, a, 0, 0, 0);
            #pragma unroll
            for (int r = 0; r < 4; ++r) {
                float z = a[r] + bias1[16 * m + drow0 + r];
                enh[m][r] = Dw[m][r] / (1.f + expf(-z));
            }
        }
    }
    __syncthreads();
    #pragma unroll
    for (int m = 0; m < 4; ++m)
        #pragma unroll
        for (int r = 0; r < 4; ++r)
            As[(16 * m + drow0 + r) * 64 + bcol] = enh[m][r];
    __syncthreads();

    // ---- stage3: fusz = Wf'@[enh; x] + bias2
    f32x4 D3[4];
    {
        bf16x8 fA[4][4];
        #pragma unroll
        for (int t = 0; t < 4; ++t)
            #pragma unroll
            for (int m = 0; m < 4; ++m)
                fA[t][m] = *(const bf16x8*)(WfA + ((t * 4 + m) * 64 + lane) * 8);
        bf16x8 B0 = loadB(As, 0), B1 = loadB(As, 32);
        bf16x8 B2 = loadB(Xs, 0), B3 = loadB(Xs, 32);
        #pragma unroll
        for (int m = 0; m < 4; ++m) {
            f32x4 a = {0.f, 0.f, 0.f, 0.f};
            a = __builtin_amdgcn_mfma_f32_16x16x32_bf16(fA[0][m], B0, a, 0, 0, 0);
            a = __builtin_amdgcn_mfma_f32_16x16x32_bf16(fA[1][m], B1, a, 0, 0, 0);
            a = __builtin_amdgcn_mfma_f32_16x16x32_bf16(fA[2][m], B2, a, 0, 0, 0);
            a = __builtin_amdgcn_mfma_f32_16x16x32_bf16(fA[3][m], B3, a, 0, 0, 0);
            #pragma unroll
            for (int r = 0; r < 4; ++r) a[r] += bias2[16 * m + drow0 + r];
            D3[m] = a;
        }
    }
    __syncthreads();
    #pragma unroll
    for (int m = 0; m < 4; ++m)
        #pragma unroll
        for (int r = 0; r < 4; ++r)
            As[(16 * m + drow0 + r) * 64 + bcol] = D3[m][r];
    __syncthreads();

    // ---- stage4: out = Wp@fusz + bp
    f32x4 D4[4];
    {
        bf16x8 qA[2][4];
        #pragma unroll
        for (int t = 0; t < 2; ++t)
            #pragma unroll
            for (int m = 0; m < 4; ++m)
                qA[t][m] = *(const bf16x8*)(WpA + ((t * 4 + m) * 64 + lane) * 8);
        bf16x8 B0 = loadB(As, 0), B1 = loadB(As, 32);
        #pragma unroll
        for (int m = 0; m < 4; ++m) {
            f32x4 a = {0.f, 0.f, 0.f, 0.f};
            a = __builtin_amdgcn_mfma_f32_16x16x32_bf16(qA[0][m], B0, a, 0, 0, 0);
            a = __builtin_amdgcn_mfma_f32_16x16x32_bf16(qA[1][m], B1, a, 0, 0, 0);
            #pragma unroll
            for (int r = 0; r < 4; ++r) a[r] += bp[16 * m + drow0 + r];
            D4[m] = a;
        }
    }
    __syncthreads();
    #pragma unroll
    for (int m = 0; m < 4; ++m)
        #pragma unroll
        for (int r = 0; r < 4; ++r)
            As[(16 * m + drow0 + r) * 64 + bcol] = D4[m][r];
    __syncthreads();
    // coalesced store: thread -> (row = tid>>2, 16 pos)
    const int row = tid >> 2, q = tid & 3;
    #pragma unroll
    for (int j = 0; j < 4; ++j) {
        int p = q * 4 + j * 16;
        *(float4*)(out + ((long long)b * 64 + row) * NPOS + n0 + p) =
            *(const float4*)(As + row * 64 + p);
    }
}

extern "C" void kernel_launch(void* const* d_in, const int* in_sizes, int n_in,
                              void* d_out, int out_size, void* d_ws, size_t ws_size,
                              hipStream_t stream) {
    (void)in_sizes; (void)n_in; (void)out_size; (void)ws_size;
    const float* x     = (const float*)d_in[0];
    const float* w_qkv = (const float*)d_in[1];
    const float* b_qkv = (const float*)d_in[2];
    const float* w_dw  = (const float*)d_in[3];
    const float* b_dw  = (const float*)d_in[4];
    const float* temp  = (const float*)d_in[5];
    const float* aw    = (const float*)d_in[6];
    const float* w_rec = (const float*)d_in[7];
    const float* b_rec = (const float*)d_in[8];
    const float* bn1g  = (const float*)d_in[9];
    const float* bn1b  = (const float*)d_in[10];
    const float* w_fus = (const float*)d_in[11];
    const float* b_fus = (const float*)d_in[12];
    const float* bn2g  = (const float*)d_in[13];
    const float* bn2b  = (const float*)d_in[14];
    const float* w_prj = (const float*)d_in[15];
    const float* b_prj = (const float*)d_in[16];
    float* out = (float*)d_out;
    float* ws  = (float*)d_ws;

    float* qkv  = ws;                       // 2*192*65536 = 25165824 floats
    float* qkv2 = qkv + 25165824;           // 25165824 floats
    float* part = qkv2 + 25165824;          // 16*128*80 = 163840
    float* gram = part + 163840;            // 1280
    float* P    = gram + 1280;              // 1024
    float* bias1 = P + 1024;                // 64
    float* bias2 = bias1 + 64;              // 64
    short* WqA  = (short*)(bias2 + 64);     // 12288 shorts
    short* WrA  = WqA + 12288;              // 4096 shorts
    short* WfA  = WrA + 4096;               // 8192 shorts
    short* WpA  = WfA + 8192;               // 4096 shorts
    short* PAb  = WpA + 4096;               // 8192 shorts

    k0_prep<<<113, 256, 0, stream>>>(w_qkv, w_rec, w_fus, w_prj, b_rec, bn1g, bn1b,
                                     b_fus, bn2g, bn2b, WqA, WrA, WfA, WpA, bias1, bias2);
    k1_qkv<<<2048, 256, 0, stream>>>(x, WqA, b_qkv, qkv);
    k2_dw<<<6144, 256, 0, stream>>>(qkv, w_dw, b_dw, qkv2);
    k3_gram<<<16 * NCHUNK, 256, 0, stream>>>(qkv2, part);
    k3b_reduce<<<5, 256, 0, stream>>>(part, gram);
    k4_combine<<<1, 128, 0, stream>>>(gram, temp, aw, P);
    k4b_pfrag<<<32, 256, 0, stream>>>(P, PAb);
    k5_tail<<<2048, 256, 0, stream>>>(qkv2, x, PAb, WrA, WfA, WpA,
                                      bias1, bias2, b_prj, out);
}

// Round 9
// 199.920 us; speedup vs baseline: 1.6006x; 1.0048x over previous
//
#include <hip/hip_runtime.h>
#include <math.h>

#define NPOS 65536          // D*H*W = 16*64*64
#define DD 16
#define HHH 64
#define WWW 64
#define NCHUNK 128

typedef __attribute__((ext_vector_type(8))) short bf16x8;   // 8 bf16 (4 VGPR)
typedef __attribute__((ext_vector_type(4))) float f32x4;

static __device__ __forceinline__ short f2bf(float f) {
    union { float f; unsigned u; } v; v.f = f;
    unsigned r = (v.u + 0x7FFFu + ((v.u >> 16) & 1u)) >> 16;
    return (short)r;
}

// ---------------- K0: MFMA A-frag weight prep (BN folded) ----------------
// A-frag layout (mfma_f32_16x16x32_bf16): lane l holds A[row=16m+(l&15)]
// [k=32t+(l>>4)*8+e], e=0..7.
__global__ void k0_prep(const float* __restrict__ Wq,
                        const float* __restrict__ Wr, const float* __restrict__ Wf,
                        const float* __restrict__ Wp,
                        const float* __restrict__ brec,
                        const float* __restrict__ bn1g, const float* __restrict__ bn1b,
                        const float* __restrict__ bfus,
                        const float* __restrict__ bn2g, const float* __restrict__ bn2b,
                        short* __restrict__ WqA, short* __restrict__ WrA,
                        short* __restrict__ WfA, short* __restrict__ WpA,
                        float* __restrict__ bias1, float* __restrict__ bias2) {
    const float invs = 1.0f / sqrtf(1.0f + 1e-5f);
    int idx = blockIdx.x * 256 + threadIdx.x;
    if (idx < 12288) {   // WqA: 3 chunks x 2 K-tiles x 4 M-tiles
        int e = idx & 7, l = (idx >> 3) & 63, m = (idx >> 9) & 3;
        int t = (idx >> 11) & 1, c = idx >> 12;
        int out = c*64 + 16*m + (l & 15), k = 32*t + ((l >> 4) << 3) + e;
        WqA[idx] = f2bf(Wq[out*64 + k]);
        return;
    }
    int i = idx - 12288;
    if (i < 4096) {      // WrA: 2 K-tiles x 4 M-tiles, bn1 scale folded per out-row
        int e = i & 7, l = (i >> 3) & 63, m = (i >> 9) & 3, t = (i >> 11) & 1;
        int out = 16*m + (l & 15), k = 32*t + ((l >> 4) << 3) + e;
        WrA[i] = f2bf(Wr[out*64 + k] * bn1g[out] * invs);
        return;
    }
    i -= 4096;
    if (i < 8192) {      // WfA: 4 K-tiles (enh 0..63, x 64..127), bn2 folded
        int e = i & 7, l = (i >> 3) & 63, m = (i >> 9) & 3, t = (i >> 11) & 3;
        int out = 16*m + (l & 15), k = 32*t + ((l >> 4) << 3) + e;
        WfA[i] = f2bf(Wf[out*128 + k] * bn2g[out] * invs);
        return;
    }
    i -= 8192;
    if (i < 4096) {      // WpA: 2 K-tiles, no BN
        int e = i & 7, l = (i >> 3) & 63, m = (i >> 9) & 3, t = (i >> 11) & 1;
        int out = 16*m + (l & 15), k = 32*t + ((l >> 4) << 3) + e;
        WpA[i] = f2bf(Wp[out*64 + k]);
        return;
    }
    i -= 4096;
    if (i < 64)       bias1[i]    = brec[i]    * bn1g[i]    * invs + bn1b[i];
    else if (i < 128) bias2[i-64] = bfus[i-64] * bn2g[i-64] * invs + bn2b[i-64];
}

// ---------------- K1: pointwise qkv conv via bf16 MFMA ----------------
__global__ __launch_bounds__(256) void k1_qkv(const float* __restrict__ x,
        const short* __restrict__ WqA, const float* __restrict__ bq,
        float* __restrict__ qkv) {
    __shared__ __align__(16) float Xs[64 * 64];
    __shared__ __align__(16) float As[64 * 64];
    const int tid = threadIdx.x, lane = tid & 63, wv = tid >> 6;
    const int blk = blockIdx.x;
    const int b = blk >> 10, n0 = (blk & 1023) << 6;
    const float* xg = x + ((long long)b * 64) * NPOS + n0;
    #pragma unroll
    for (int kk = 0; kk < 4; ++kk) {
        int idx = tid + kk * 256;            // [64ch][64pos] float4 tiles
        int ch = idx >> 4, p = (idx & 15) << 2;
        *(float4*)(Xs + ch * 64 + p) = *(const float4*)(xg + (long long)ch * NPOS + p);
    }
    const int bcol  = wv * 16 + (lane & 15);
    const int bk    = (lane >> 4) << 3;
    const int drow0 = (lane >> 4) << 2;
    __syncthreads();

    bf16x8 B0, B1;
    #pragma unroll
    for (int e = 0; e < 8; ++e) B0[e] = f2bf(Xs[(bk + e) * 64 + bcol]);
    #pragma unroll
    for (int e = 0; e < 8; ++e) B1[e] = f2bf(Xs[(32 + bk + e) * 64 + bcol]);

    #pragma unroll
    for (int c = 0; c < 3; ++c) {
        f32x4 D[4];
        #pragma unroll
        for (int m = 0; m < 4; ++m) {
            bf16x8 A0 = *(const bf16x8*)(WqA + (((c * 2 + 0) * 4 + m) * 64 + lane) * 8);
            bf16x8 A1 = *(const bf16x8*)(WqA + (((c * 2 + 1) * 4 + m) * 64 + lane) * 8);
            f32x4 a = {0.f, 0.f, 0.f, 0.f};
            a = __builtin_amdgcn_mfma_f32_16x16x32_bf16(A0, B0, a, 0, 0, 0);
            a = __builtin_amdgcn_mfma_f32_16x16x32_bf16(A1, B1, a, 0, 0, 0);
            float4 bb = *(const float4*)(bq + c * 64 + 16 * m + drow0);
            a[0] += bb.x; a[1] += bb.y; a[2] += bb.z; a[3] += bb.w;
            D[m] = a;
        }
        if (c) __syncthreads();              // As consumed by previous chunk's store
        #pragma unroll
        for (int m = 0; m < 4; ++m)
            #pragma unroll
            for (int r = 0; r < 4; ++r)
                As[(16 * m + drow0 + r) * 64 + bcol] = D[m][r];
        __syncthreads();
        const int row = tid >> 2, q = tid & 3;
        #pragma unroll
        for (int j = 0; j < 4; ++j) {
            int p = q * 4 + j * 16;
            *(float4*)(qkv + ((long long)b * 192 + c * 64 + row) * NPOS + n0 + p) =
                *(const float4*)(As + row * 64 + p);
        }
    }
}

// ---------------- K2: depthwise 3x3x3 conv via LDS stencil tile ----------------
// Conflict-free layout: row stride 72 (data at +4, halos at 3 and 68).
// Thread = (wl 0..15, oh 0..15): 4 w-outputs x 4 d-outputs. Per tap-row:
// one aligned b128 (16 lanes tile all 32 banks) + two b32 edges (2-way, free).
__global__ __launch_bounds__(256) void k2_dw(const float* __restrict__ qkv,
        const float* __restrict__ Wd, const float* __restrict__ bd,
        float* __restrict__ qkv2) {
    __shared__ __align__(16) float tile[108 * 72];
    __shared__ float wsh[28];
    const int tid = threadIdx.x;
    const int bc  = blockIdx.x >> 4;        // 0..383 = b*192 + c
    const int sub = blockIdx.x & 15;
    const int d0  = (sub >> 2) << 2;        // 0,4,8,12
    const int h0  = (sub & 3) << 4;         // 0,16,32,48
    const int c   = bc % 192;

    if (tid < 27) wsh[tid] = Wd[c * 27 + tid];
    if (tid == 31) wsh[27] = bd[c];

    const float* in = qkv + (long long)bc * NPOS;
    for (int r = tid; r < 108; r += 256) {
        tile[r * 72 + 3]  = 0.f;
        tile[r * 72 + 68] = 0.f;
    }
    for (int i = tid; i < 1728; i += 256) {
        const int r = i >> 4, q = i & 15;
        const int dd = r / 18;              // 0..5
        const int hh = r - dd * 18;         // 0..17
        const int d = d0 + dd - 1;
        const int h = h0 + hh - 1;
        float4 v = make_float4(0.f, 0.f, 0.f, 0.f);
        if (d >= 0 && d < DD && h >= 0 && h < HHH)
            v = *(const float4*)(in + (d << 12) + (h << 6) + (q << 2));
        *(float4*)(tile + r * 72 + 4 + (q << 2)) = v;
    }
    __syncthreads();

    float wreg[27];
    #pragma unroll
    for (int s = 0; s < 27; ++s) wreg[s] = wsh[s];
    const float bias = wsh[27];

    const int wl = tid & 15;                // w-group: w0 = 4*wl
    const int oh = tid >> 4;                // 0..15
    const int w0 = wl << 2;

    float acc[4][4];                        // [od][j]
    #pragma unroll
    for (int od = 0; od < 4; ++od)
        #pragma unroll
        for (int j = 0; j < 4; ++j) acc[od][j] = bias;

    #pragma unroll
    for (int kh = 0; kh < 3; ++kh) {
        #pragma unroll
        for (int dp = 0; dp < 6; ++dp) {    // tile d-plane (abs d = d0+dp-1)
            const float* row = tile + (dp * 18 + oh + kh) * 72 + 4 + w0;
            const float4 v = *(const float4*)(row);   // w0..w0+3
            const float lf = row[-1];                  // w0-1
            const float rt = row[4];                   // w0+4
            const float win[6] = {lf, v.x, v.y, v.z, v.w, rt};
            #pragma unroll
            for (int od = 0; od < 4; ++od) {
                const int kd = dp - od;     // plane dp feeds od with kd=dp-od
                if (kd < 0 || kd > 2) continue;
                const float W0 = wreg[kd * 9 + kh * 3 + 0];
                const float W1 = wreg[kd * 9 + kh * 3 + 1];
                const float W2 = wreg[kd * 9 + kh * 3 + 2];
                #pragma unroll
                for (int j = 0; j < 4; ++j)
                    acc[od][j] = fmaf(W0, win[j],
                                 fmaf(W1, win[j+1], fmaf(W2, win[j+2], acc[od][j])));
            }
        }
    }
    float* outp = qkv2 + (long long)bc * NPOS + (h0 + oh) * 64 + w0;
    #pragma unroll
    for (int od = 0; od < 4; ++od)
        *(float4*)(outp + ((d0 + od) << 12)) =
            make_float4(acc[od][0], acc[od][1], acc[od][2], acc[od][3]);
}

// ---------------- K3: Gram partials: per (b,h,chunk) -> 64 qk + 8 qq + 8 kk ----------------
__global__ __launch_bounds__(256) void k3_gram(const float* __restrict__ qkv2,
                                               float* __restrict__ partial) {
    const int blk = blockIdx.x;
    const int chunk = blk & (NCHUNK - 1);
    const int bh = blk >> 7;                  // 0..15
    const int b = bh >> 3, h = bh & 7;
    const float* qb = qkv2 + ((long long)b * 192 + h * 8) * NPOS;
    const float* kb = qb + 64 * NPOS;
    const int npc = NPOS / NCHUNK;            // 512
    const int n0 = chunk * npc;
    float vals[80];
    #pragma unroll
    for (int s = 0; s < 80; ++s) vals[s] = 0.f;
    for (int t = threadIdx.x; t < npc; t += 256) {
        int n = n0 + t;
        float qv[8], kv[8];
        #pragma unroll
        for (int i = 0; i < 8; ++i) qv[i] = qb[i * NPOS + n];
        #pragma unroll
        for (int j = 0; j < 8; ++j) kv[j] = kb[j * NPOS + n];
        #pragma unroll
        for (int i = 0; i < 8; ++i) {
            #pragma unroll
            for (int j = 0; j < 8; ++j)
                vals[i * 8 + j] = fmaf(qv[i], kv[j], vals[i * 8 + j]);
        }
        #pragma unroll
        for (int i = 0; i < 8; ++i) vals[64 + i] = fmaf(qv[i], qv[i], vals[64 + i]);
        #pragma unroll
        for (int j = 0; j < 8; ++j) vals[72 + j] = fmaf(kv[j], kv[j], vals[72 + j]);
    }
    __shared__ float red[4][80];
    const int lane = threadIdx.x & 63, wv = threadIdx.x >> 6;
    #pragma unroll
    for (int s = 0; s < 80; ++s) {
        float v = vals[s];
        #pragma unroll
        for (int off = 32; off > 0; off >>= 1)
            v += __shfl_xor(v, off, 64);
        if (lane == 0) red[wv][s] = v;
    }
    __syncthreads();
    if (threadIdx.x < 80)
        partial[((long long)bh * NCHUNK + chunk) * 80 + threadIdx.x] =
            red[0][threadIdx.x] + red[1][threadIdx.x] + red[2][threadIdx.x] + red[3][threadIdx.x];
}

// ---------------- K3b: deterministic chunk reduction ----------------
__global__ void k3b_reduce(const float* __restrict__ partial, float* __restrict__ gram) {
    int s = blockIdx.x * 256 + threadIdx.x;
    if (s >= 16 * 80) return;
    int bh = s / 80, slot = s % 80;
    float acc = 0.f;
    for (int c = 0; c < NCHUNK; ++c)
        acc += partial[((long long)bh * NCHUNK + c) * 80 + slot];
    gram[s] = acc;
}

// ---------------- K4: attn -> topk mask softmax -> combined P ----------------
__global__ void k4_combine(const float* __restrict__ gram, const float* __restrict__ temp,
                           const float* __restrict__ aw, float* __restrict__ P) {
    int t = threadIdx.x;               // one (b,h,i) row per thread; 128 threads
    if (t >= 128) return;
    int bh = t >> 3, i = t & 7;
    int h = bh & 7;
    const float* g = gram + bh * 80;
    float qn = fmaxf(sqrtf(g[64 + i]), 1e-12f);
    float tp = temp[h];
    float attn[8];
    #pragma unroll
    for (int j = 0; j < 8; ++j) {
        float kn = fmaxf(sqrtf(g[72 + j]), 1e-12f);
        attn[j] = g[i * 8 + j] / (qn * kn) * tp;
    }
    float awv[4];
    float am = -3.4e38f;
    for (int r = 0; r < 4; ++r) { awv[r] = aw[r]; am = fmaxf(am, awv[r]); }
    float asum = 0.f;
    for (int r = 0; r < 4; ++r) { awv[r] = expf(awv[r] - am); asum += awv[r]; }
    const int kvs[4] = {4, 5, 6, 6};   // int(8*ratio) for 0.5,0.67,0.75,0.8
    float Pacc[8];
    #pragma unroll
    for (int j = 0; j < 8; ++j) Pacc[j] = 0.f;
    for (int r = 0; r < 4; ++r) {
        float sw = awv[r] / asum;
        int kv = kvs[r];
        bool sel[8];
        #pragma unroll
        for (int j = 0; j < 8; ++j) sel[j] = false;
        for (int m = 0; m < kv; ++m) {     // exact top_k: ties -> smallest index
            int best = 0; float bv = -3.4e38f;
            for (int j = 0; j < 8; ++j)
                if (!sel[j] && attn[j] > bv) { bv = attn[j]; best = j; }
            sel[best] = true;
        }
        float mx = -3.4e38f;
        for (int j = 0; j < 8; ++j) if (sel[j]) mx = fmaxf(mx, attn[j]);
        float es = 0.f, e[8];
        for (int j = 0; j < 8; ++j) { e[j] = sel[j] ? expf(attn[j] - mx) : 0.f; es += e[j]; }
        for (int j = 0; j < 8; ++j) Pacc[j] += sw * e[j] / es;
    }
    for (int j = 0; j < 8; ++j) P[t * 8 + j] = Pacc[j];
}

// ---------------- K4b: expand P to block-diagonal 64x64 A-frags ----------------
__global__ void k4b_pfrag(const float* __restrict__ P, short* __restrict__ PA) {
    int idx = blockIdx.x * 256 + threadIdx.x;   // 8192 = 2b x 2t x 4m x 64l x 8e
    int e = idx & 7, l = (idx >> 3) & 63, m = (idx >> 9) & 3;
    int t = (idx >> 11) & 1, b = idx >> 12;
    int out = 16*m + (l & 15), k = 32*t + ((l >> 4) << 3) + e;
    float v = ((k >> 3) == (out >> 3)) ? P[(b * 64 + out) * 8 + (k & 7)] : 0.f;
    PA[idx] = f2bf(v);
}

// ---------------- K5: fused tail via bf16 MFMA ----------------
__global__ __launch_bounds__(256) void k5_tail(
        const float* __restrict__ qkv2, const float* __restrict__ x,
        const short* __restrict__ PA, const short* __restrict__ WrA,
        const short* __restrict__ WfA, const short* __restrict__ WpA,
        const float* __restrict__ bias1, const float* __restrict__ bias2,
        const float* __restrict__ bp, float* __restrict__ out) {
    __shared__ __align__(16) float As[64 * 64];
    __shared__ __align__(16) float Xs[64 * 64];
    const int tid = threadIdx.x, lane = tid & 63, wv = tid >> 6;
    const int blk = blockIdx.x;
    const int b = blk >> 10, n0 = (blk & 1023) << 6;
    const float* vg = qkv2 + ((long long)b * 192 + 128) * NPOS + n0;
    const float* xg = x + ((long long)b * 64) * NPOS + n0;
    #pragma unroll
    for (int kk = 0; kk < 4; ++kk) {
        int idx = tid + kk * 256;            // [64ch][64pos] float4 tiles
        int ch = idx >> 4, p = (idx & 15) << 2;
        *(float4*)(As + ch * 64 + p) = *(const float4*)(vg + (long long)ch * NPOS + p);
        *(float4*)(Xs + ch * 64 + p) = *(const float4*)(xg + (long long)ch * NPOS + p);
    }
    bf16x8 pA[2][4];
    #pragma unroll
    for (int t = 0; t < 2; ++t)
        #pragma unroll
        for (int m = 0; m < 4; ++m)
            pA[t][m] = *(const bf16x8*)(PA + (((b * 2 + t) * 4 + m) * 64 + lane) * 8);
    const int bcol  = wv * 16 + (lane & 15);   // B col / D col
    const int bk    = (lane >> 4) << 3;        // B/A k-slice base
    const int drow0 = (lane >> 4) << 2;        // D row base within 16-tile
    __syncthreads();

    auto loadB = [&](const float* S, int kbase) {
        bf16x8 r;
        #pragma unroll
        for (int e = 0; e < 8; ++e) r[e] = f2bf(S[(kbase + bk + e) * 64 + bcol]);
        return r;
    };

    // ---- stage1: weighted = P_blockdiag @ v
    f32x4 Dw[4];
    {
        bf16x8 B0 = loadB(As, 0), B1 = loadB(As, 32);
        #pragma unroll
        for (int m = 0; m < 4; ++m) {
            f32x4 a = {0.f, 0.f, 0.f, 0.f};
            a = __builtin_amdgcn_mfma_f32_16x16x32_bf16(pA[0][m], B0, a, 0, 0, 0);
            a = __builtin_amdgcn_mfma_f32_16x16x32_bf16(pA[1][m], B1, a, 0, 0, 0);
            Dw[m] = a;
        }
    }
    __syncthreads();
    #pragma unroll
    for (int m = 0; m < 4; ++m)
        #pragma unroll
        for (int r = 0; r < 4; ++r)
            As[(16 * m + drow0 + r) * 64 + bcol] = Dw[m][r];
    __syncthreads();

    // ---- stage2: rec = sigmoid(Wr'@weighted + bias1); enh = weighted*rec
    float enh[4][4];
    {
        bf16x8 rA[2][4];
        #pragma unroll
        for (int t = 0; t < 2; ++t)
            #pragma unroll
            for (int m = 0; m < 4; ++m)
                rA[t][m] = *(const bf16x8*)(WrA + ((t * 4 + m) * 64 + lane) * 8);
        bf16x8 B0 = loadB(As, 0), B1 = loadB(As, 32);
        #pragma unroll
        for (int m = 0; m < 4; ++m) {
            f32x4 a = {0.f, 0.f, 0.f, 0.f};
            a = __builtin_amdgcn_mfma_f32_16x16x32_bf16(rA[0][m], B0, a, 0, 0, 0);
            a = __builtin_amdgcn_mfma_f32_16x16x32_bf16(rA[1][m], B1, a, 0, 0, 0);
            #pragma unroll
            for (int r = 0; r < 4; ++r) {
                float z = a[r] + bias1[16 * m + drow0 + r];
                enh[m][r] = Dw[m][r] / (1.f + expf(-z));
            }
        }
    }
    __syncthreads();
    #pragma unroll
    for (int m = 0; m < 4; ++m)
        #pragma unroll
        for (int r = 0; r < 4; ++r)
            As[(16 * m + drow0 + r) * 64 + bcol] = enh[m][r];
    __syncthreads();

    // ---- stage3: fusz = Wf'@[enh; x] + bias2
    f32x4 D3[4];
    {
        bf16x8 fA[4][4];
        #pragma unroll
        for (int t = 0; t < 4; ++t)
            #pragma unroll
            for (int m = 0; m < 4; ++m)
                fA[t][m] = *(const bf16x8*)(WfA + ((t * 4 + m) * 64 + lane) * 8);
        bf16x8 B0 = loadB(As, 0), B1 = loadB(As, 32);
        bf16x8 B2 = loadB(Xs, 0), B3 = loadB(Xs, 32);
        #pragma unroll
        for (int m = 0; m < 4; ++m) {
            f32x4 a = {0.f, 0.f, 0.f, 0.f};
            a = __builtin_amdgcn_mfma_f32_16x16x32_bf16(fA[0][m], B0, a, 0, 0, 0);
            a = __builtin_amdgcn_mfma_f32_16x16x32_bf16(fA[1][m], B1, a, 0, 0, 0);
            a = __builtin_amdgcn_mfma_f32_16x16x32_bf16(fA[2][m], B2, a, 0, 0, 0);
            a = __builtin_amdgcn_mfma_f32_16x16x32_bf16(fA[3][m], B3, a, 0, 0, 0);
            #pragma unroll
            for (int r = 0; r < 4; ++r) a[r] += bias2[16 * m + drow0 + r];
            D3[m] = a;
        }
    }
    __syncthreads();
    #pragma unroll
    for (int m = 0; m < 4; ++m)
        #pragma unroll
        for (int r = 0; r < 4; ++r)
            As[(16 * m + drow0 + r) * 64 + bcol] = D3[m][r];
    __syncthreads();

    // ---- stage4: out = Wp@fusz + bp
    f32x4 D4[4];
    {
        bf16x8 qA[2][4];
        #pragma unroll
        for (int t = 0; t < 2; ++t)
            #pragma unroll
            for (int m = 0; m < 4; ++m)
                qA[t][m] = *(const bf16x8*)(WpA + ((t * 4 + m) * 64 + lane) * 8);
        bf16x8 B0 = loadB(As, 0), B1 = loadB(As, 32);
        #pragma unroll
        for (int m = 0; m < 4; ++m) {
            f32x4 a = {0.f, 0.f, 0.f, 0.f};
            a = __builtin_amdgcn_mfma_f32_16x16x32_bf16(qA[0][m], B0, a, 0, 0, 0);
            a = __builtin_amdgcn_mfma_f32_16x16x32_bf16(qA[1][m], B1, a, 0, 0, 0);
            #pragma unroll
            for (int r = 0; r < 4; ++r) a[r] += bp[16 * m + drow0 + r];
            D4[m] = a;
        }
    }
    __syncthreads();
    #pragma unroll
    for (int m = 0; m < 4; ++m)
        #pragma unroll
        for (int r = 0; r < 4; ++r)
            As[(16 * m + drow0 + r) * 64 + bcol] = D4[m][r];
    __syncthreads();
    // coalesced store: thread -> (row = tid>>2, 16 pos)
    const int row = tid >> 2, q = tid & 3;
    #pragma unroll
    for (int j = 0; j < 4; ++j) {
        int p = q * 4 + j * 16;
        *(float4*)(out + ((long long)b * 64 + row) * NPOS + n0 + p) =
            *(const float4*)(As + row * 64 + p);
    }
}

extern "C" void kernel_launch(void* const* d_in, const int* in_sizes, int n_in,
                              void* d_out, int out_size, void* d_ws, size_t ws_size,
                              hipStream_t stream) {
    (void)in_sizes; (void)n_in; (void)out_size; (void)ws_size;
    const float* x     = (const float*)d_in[0];
    const float* w_qkv = (const float*)d_in[1];
    const float* b_qkv = (const float*)d_in[2];
    const float* w_dw  = (const float*)d_in[3];
    const float* b_dw  = (const float*)d_in[4];
    const float* temp  = (const float*)d_in[5];
    const float* aw    = (const float*)d_in[6];
    const float* w_rec = (const float*)d_in[7];
    const float* b_rec = (const float*)d_in[8];
    const float* bn1g  = (const float*)d_in[9];
    const float* bn1b  = (const float*)d_in[10];
    const float* w_fus = (const float*)d_in[11];
    const float* b_fus = (const float*)d_in[12];
    const float* bn2g  = (const float*)d_in[13];
    const float* bn2b  = (const float*)d_in[14];
    const float* w_prj = (const float*)d_in[15];
    const float* b_prj = (const float*)d_in[16];
    float* out = (float*)d_out;
    float* ws  = (float*)d_ws;

    float* qkv  = ws;                       // 2*192*65536 = 25165824 floats
    float* qkv2 = qkv + 25165824;           // 25165824 floats
    float* part = qkv2 + 25165824;          // 16*128*80 = 163840
    float* gram = part + 163840;            // 1280
    float* P    = gram + 1280;              // 1024
    float* bias1 = P + 1024;                // 64
    float* bias2 = bias1 + 64;              // 64
    short* WqA  = (short*)(bias2 + 64);     // 12288 shorts
    short* WrA  = WqA + 12288;              // 4096 shorts
    short* WfA  = WrA + 4096;               // 8192 shorts
    short* WpA  = WfA + 8192;               // 4096 shorts
    short* PAb  = WpA + 4096;               // 8192 shorts

    k0_prep<<<113, 256, 0, stream>>>(w_qkv, w_rec, w_fus, w_prj, b_rec, bn1g, bn1b,
                                     b_fus, bn2g, bn2b, WqA, WrA, WfA, WpA, bias1, bias2);
    k1_qkv<<<2048, 256, 0, stream>>>(x, WqA, b_qkv, qkv);
    k2_dw<<<6144, 256, 0, stream>>>(qkv, w_dw, b_dw, qkv2);
    k3_gram<<<16 * NCHUNK, 256, 0, stream>>>(qkv2, part);
    k3b_reduce<<<5, 256, 0, stream>>>(part, gram);
    k4_combine<<<1, 128, 0, stream>>>(gram, temp, aw, P);
    k4b_pfrag<<<32, 256, 0, stream>>>(P, PAb);
    k5_tail<<<2048, 256, 0, stream>>>(qkv2, x, PAb, WrA, WfA, WpA,
                                      bias1, bias2, b_prj, out);
}

// Round 10
// 165.315 us; speedup vs baseline: 1.9357x; 1.2093x over previous
//
#include <hip/hip_runtime.h>
#include <math.h>

#define NPOS 65536          // D*H*W = 16*64*64
#define DD 16
#define HHH 64
#define WWW 64
#define NCHUNK 128

typedef __attribute__((ext_vector_type(8))) short bf16x8;   // 8 bf16 (4 VGPR)
typedef __attribute__((ext_vector_type(4))) short s16x4;
typedef __attribute__((ext_vector_type(4))) float f32x4;

static __device__ __forceinline__ short f2bf(float f) {
    union { float f; unsigned u; } v; v.f = f;
    unsigned r = (v.u + 0x7FFFu + ((v.u >> 16) & 1u)) >> 16;
    return (short)r;
}
static __device__ __forceinline__ float bf2f(short s) {
    union { unsigned u; float f; } v; v.u = ((unsigned)(unsigned short)s) << 16;
    return v.f;
}

// ---------------- K0: MFMA A-frag weight prep (BN folded) ----------------
__global__ void k0_prep(const float* __restrict__ Wq,
                        const float* __restrict__ Wr, const float* __restrict__ Wf,
                        const float* __restrict__ Wp,
                        const float* __restrict__ brec,
                        const float* __restrict__ bn1g, const float* __restrict__ bn1b,
                        const float* __restrict__ bfus,
                        const float* __restrict__ bn2g, const float* __restrict__ bn2b,
                        short* __restrict__ WqA, short* __restrict__ WrA,
                        short* __restrict__ WfA, short* __restrict__ WpA,
                        float* __restrict__ bias1, float* __restrict__ bias2) {
    const float invs = 1.0f / sqrtf(1.0f + 1e-5f);
    int idx = blockIdx.x * 256 + threadIdx.x;
    if (idx < 12288) {   // WqA: 3 chunks x 2 K-tiles x 4 M-tiles
        int e = idx & 7, l = (idx >> 3) & 63, m = (idx >> 9) & 3;
        int t = (idx >> 11) & 1, c = idx >> 12;
        int out = c*64 + 16*m + (l & 15), k = 32*t + ((l >> 4) << 3) + e;
        WqA[idx] = f2bf(Wq[out*64 + k]);
        return;
    }
    int i = idx - 12288;
    if (i < 4096) {      // WrA
        int e = i & 7, l = (i >> 3) & 63, m = (i >> 9) & 3, t = (i >> 11) & 1;
        int out = 16*m + (l & 15), k = 32*t + ((l >> 4) << 3) + e;
        WrA[i] = f2bf(Wr[out*64 + k] * bn1g[out] * invs);
        return;
    }
    i -= 4096;
    if (i < 8192) {      // WfA
        int e = i & 7, l = (i >> 3) & 63, m = (i >> 9) & 3, t = (i >> 11) & 3;
        int out = 16*m + (l & 15), k = 32*t + ((l >> 4) << 3) + e;
        WfA[i] = f2bf(Wf[out*128 + k] * bn2g[out] * invs);
        return;
    }
    i -= 8192;
    if (i < 4096) {      // WpA
        int e = i & 7, l = (i >> 3) & 63, m = (i >> 9) & 3, t = (i >> 11) & 1;
        int out = 16*m + (l & 15), k = 32*t + ((l >> 4) << 3) + e;
        WpA[i] = f2bf(Wp[out*64 + k]);
        return;
    }
    i -= 4096;
    if (i < 64)       bias1[i]    = brec[i]    * bn1g[i]    * invs + bn1b[i];
    else if (i < 128) bias2[i-64] = bfus[i-64] * bn2g[i-64] * invs + bn2b[i-64];
}

// ---------------- K1: pointwise qkv conv via bf16 MFMA (bf16 output) --------
__global__ __launch_bounds__(256) void k1_qkv(const float* __restrict__ x,
        const short* __restrict__ WqA, const float* __restrict__ bq,
        short* __restrict__ qkv) {
    __shared__ __align__(16) float Xs[64 * 64];
    __shared__ __align__(16) float As[64 * 64];
    const int tid = threadIdx.x, lane = tid & 63, wv = tid >> 6;
    const int blk = blockIdx.x;
    const int b = blk >> 10, n0 = (blk & 1023) << 6;
    const float* xg = x + ((long long)b * 64) * NPOS + n0;
    #pragma unroll
    for (int kk = 0; kk < 4; ++kk) {
        int idx = tid + kk * 256;
        int ch = idx >> 4, p = (idx & 15) << 2;
        *(float4*)(Xs + ch * 64 + p) = *(const float4*)(xg + (long long)ch * NPOS + p);
    }
    const int bcol  = wv * 16 + (lane & 15);
    const int bk    = (lane >> 4) << 3;
    const int drow0 = (lane >> 4) << 2;
    __syncthreads();

    bf16x8 B0, B1;
    #pragma unroll
    for (int e = 0; e < 8; ++e) B0[e] = f2bf(Xs[(bk + e) * 64 + bcol]);
    #pragma unroll
    for (int e = 0; e < 8; ++e) B1[e] = f2bf(Xs[(32 + bk + e) * 64 + bcol]);

    #pragma unroll
    for (int c = 0; c < 3; ++c) {
        f32x4 D[4];
        #pragma unroll
        for (int m = 0; m < 4; ++m) {
            bf16x8 A0 = *(const bf16x8*)(WqA + (((c * 2 + 0) * 4 + m) * 64 + lane) * 8);
            bf16x8 A1 = *(const bf16x8*)(WqA + (((c * 2 + 1) * 4 + m) * 64 + lane) * 8);
            f32x4 a = {0.f, 0.f, 0.f, 0.f};
            a = __builtin_amdgcn_mfma_f32_16x16x32_bf16(A0, B0, a, 0, 0, 0);
            a = __builtin_amdgcn_mfma_f32_16x16x32_bf16(A1, B1, a, 0, 0, 0);
            float4 bb = *(const float4*)(bq + c * 64 + 16 * m + drow0);
            a[0] += bb.x; a[1] += bb.y; a[2] += bb.z; a[3] += bb.w;
            D[m] = a;
        }
        if (c) __syncthreads();
        #pragma unroll
        for (int m = 0; m < 4; ++m)
            #pragma unroll
            for (int r = 0; r < 4; ++r)
                As[(16 * m + drow0 + r) * 64 + bcol] = D[m][r];
        __syncthreads();
        const int row = tid >> 2, q = tid & 3;
        bf16x8 o0, o1;
        #pragma unroll
        for (int j = 0; j < 8; ++j) {
            o0[j] = f2bf(As[row * 64 + q * 16 + j]);
            o1[j] = f2bf(As[row * 64 + q * 16 + 8 + j]);
        }
        short* op = qkv + ((long long)b * 192 + c * 64 + row) * NPOS + n0 + q * 16;
        *(bf16x8*)(op)     = o0;
        *(bf16x8*)(op + 8) = o1;
    }
}

// ---------------- K2: depthwise 3x3x3 conv, bf16 in/out, shuffle edges ------
// Thread = (wl 0..15, oh 0..15): 4 w x 4 d outputs. Per tap-row: one aligned
// b128 (contiguous per 16-lane group, conflict-free) + 2 __shfl for edges
// (replaces the 8-way-conflicting scalar b32 reads).
__global__ __launch_bounds__(256) void k2_dw(const short* __restrict__ qkv,
        const float* __restrict__ Wd, const float* __restrict__ bd,
        short* __restrict__ qkv2) {
    __shared__ __align__(16) float tile[108 * 72];
    __shared__ float wsh[28];
    const int tid = threadIdx.x;
    const int lane = tid & 63;
    const int bc  = blockIdx.x >> 4;        // 0..383 = b*192 + c
    const int sub = blockIdx.x & 15;
    const int d0  = (sub >> 2) << 2;        // 0,4,8,12
    const int h0  = (sub & 3) << 4;         // 0,16,32,48
    const int c   = bc % 192;

    if (tid < 27) wsh[tid] = Wd[c * 27 + tid];
    if (tid == 31) wsh[27] = bd[c];

    const short* in = qkv + (long long)bc * NPOS;
    for (int i = tid; i < 864; i += 256) {   // 108 rows x 8 chunks of 8 bf16
        const int r = i >> 3, q8 = i & 7;
        const int dd = r / 18;               // 0..5
        const int hh = r - dd * 18;          // 0..17
        const int d = d0 + dd - 1;
        const int h = h0 + hh - 1;
        float4 f0 = make_float4(0.f, 0.f, 0.f, 0.f);
        float4 f1 = make_float4(0.f, 0.f, 0.f, 0.f);
        if (d >= 0 && d < DD && h >= 0 && h < HHH) {
            bf16x8 raw = *(const bf16x8*)(in + (d << 12) + (h << 6) + (q8 << 3));
            f0 = make_float4(bf2f(raw[0]), bf2f(raw[1]), bf2f(raw[2]), bf2f(raw[3]));
            f1 = make_float4(bf2f(raw[4]), bf2f(raw[5]), bf2f(raw[6]), bf2f(raw[7]));
        }
        *(float4*)(tile + r * 72 + (q8 << 3))     = f0;
        *(float4*)(tile + r * 72 + (q8 << 3) + 4) = f1;
    }
    __syncthreads();

    float wreg[27];
    #pragma unroll
    for (int s = 0; s < 27; ++s) wreg[s] = wsh[s];
    const float bias = wsh[27];

    const int wl = tid & 15;                // w-group: w0 = 4*wl
    const int oh = tid >> 4;                // 0..15
    const int w0 = wl << 2;

    float acc[4][4];                        // [od][j]
    #pragma unroll
    for (int od = 0; od < 4; ++od)
        #pragma unroll
        for (int j = 0; j < 4; ++j) acc[od][j] = bias;

    #pragma unroll
    for (int kh = 0; kh < 3; ++kh) {
        #pragma unroll
        for (int dp = 0; dp < 6; ++dp) {    // tile d-plane (abs d = d0+dp-1)
            const float* row = tile + (dp * 18 + oh + kh) * 72 + w0;
            const float4 v = *(const float4*)(row);
            float lf = __shfl(v.w, lane - 1, 64);
            float rt = __shfl(v.x, lane + 1, 64);
            lf = (wl == 0)  ? 0.f : lf;     // w=-1 zero pad
            rt = (wl == 15) ? 0.f : rt;     // w=64 zero pad
            const float win[6] = {lf, v.x, v.y, v.z, v.w, rt};
            #pragma unroll
            for (int od = 0; od < 4; ++od) {
                const int kd = dp - od;     // plane dp feeds od with kd=dp-od
                if (kd < 0 || kd > 2) continue;
                const float W0 = wreg[kd * 9 + kh * 3 + 0];
                const float W1 = wreg[kd * 9 + kh * 3 + 1];
                const float W2 = wreg[kd * 9 + kh * 3 + 2];
                #pragma unroll
                for (int j = 0; j < 4; ++j)
                    acc[od][j] = fmaf(W0, win[j],
                                 fmaf(W1, win[j+1], fmaf(W2, win[j+2], acc[od][j])));
            }
        }
    }
    short* outp = qkv2 + (long long)bc * NPOS + (h0 + oh) * 64 + w0;
    #pragma unroll
    for (int od = 0; od < 4; ++od) {
        s16x4 o;
        #pragma unroll
        for (int j = 0; j < 4; ++j) o[j] = f2bf(acc[od][j]);
        *(s16x4*)(outp + ((d0 + od) << 12)) = o;
    }
}

// ---------------- K3: Gram partials (bf16 input) ----------------
__global__ __launch_bounds__(256) void k3_gram(const short* __restrict__ qkv2,
                                               float* __restrict__ partial) {
    const int blk = blockIdx.x;
    const int chunk = blk & (NCHUNK - 1);
    const int bh = blk >> 7;                  // 0..15
    const int b = bh >> 3, h = bh & 7;
    const short* qb = qkv2 + ((long long)b * 192 + h * 8) * NPOS;
    const short* kb = qb + 64 * NPOS;
    const int npc = NPOS / NCHUNK;            // 512
    const int n0 = chunk * npc;
    float vals[80];
    #pragma unroll
    for (int s = 0; s < 80; ++s) vals[s] = 0.f;
    for (int t = threadIdx.x; t < npc; t += 256) {
        int n = n0 + t;
        float qv[8], kv[8];
        #pragma unroll
        for (int i = 0; i < 8; ++i) qv[i] = bf2f(qb[(long long)i * NPOS + n]);
        #pragma unroll
        for (int j = 0; j < 8; ++j) kv[j] = bf2f(kb[(long long)j * NPOS + n]);
        #pragma unroll
        for (int i = 0; i < 8; ++i) {
            #pragma unroll
            for (int j = 0; j < 8; ++j)
                vals[i * 8 + j] = fmaf(qv[i], kv[j], vals[i * 8 + j]);
        }
        #pragma unroll
        for (int i = 0; i < 8; ++i) vals[64 + i] = fmaf(qv[i], qv[i], vals[64 + i]);
        #pragma unroll
        for (int j = 0; j < 8; ++j) vals[72 + j] = fmaf(kv[j], kv[j], vals[72 + j]);
    }
    __shared__ float red[4][80];
    const int lane = threadIdx.x & 63, wv = threadIdx.x >> 6;
    #pragma unroll
    for (int s = 0; s < 80; ++s) {
        float v = vals[s];
        #pragma unroll
        for (int off = 32; off > 0; off >>= 1)
            v += __shfl_xor(v, off, 64);
        if (lane == 0) red[wv][s] = v;
    }
    __syncthreads();
    if (threadIdx.x < 80)
        partial[((long long)bh * NCHUNK + chunk) * 80 + threadIdx.x] =
            red[0][threadIdx.x] + red[1][threadIdx.x] + red[2][threadIdx.x] + red[3][threadIdx.x];
}

// ---------------- K3b: deterministic chunk reduction ----------------
__global__ void k3b_reduce(const float* __restrict__ partial, float* __restrict__ gram) {
    int s = blockIdx.x * 256 + threadIdx.x;
    if (s >= 16 * 80) return;
    int bh = s / 80, slot = s % 80;
    float acc = 0.f;
    for (int c = 0; c < NCHUNK; ++c)
        acc += partial[((long long)bh * NCHUNK + c) * 80 + slot];
    gram[s] = acc;
}

// ---------------- K4: attn -> topk mask softmax -> combined P ----------------
__global__ void k4_combine(const float* __restrict__ gram, const float* __restrict__ temp,
                           const float* __restrict__ aw, float* __restrict__ P) {
    int t = threadIdx.x;               // one (b,h,i) row per thread; 128 threads
    if (t >= 128) return;
    int bh = t >> 3, i = t & 7;
    int h = bh & 7;
    const float* g = gram + bh * 80;
    float qn = fmaxf(sqrtf(g[64 + i]), 1e-12f);
    float tp = temp[h];
    float attn[8];
    #pragma unroll
    for (int j = 0; j < 8; ++j) {
        float kn = fmaxf(sqrtf(g[72 + j]), 1e-12f);
        attn[j] = g[i * 8 + j] / (qn * kn) * tp;
    }
    float awv[4];
    float am = -3.4e38f;
    for (int r = 0; r < 4; ++r) { awv[r] = aw[r]; am = fmaxf(am, awv[r]); }
    float asum = 0.f;
    for (int r = 0; r < 4; ++r) { awv[r] = expf(awv[r] - am); asum += awv[r]; }
    const int kvs[4] = {4, 5, 6, 6};   // int(8*ratio) for 0.5,0.67,0.75,0.8
    float Pacc[8];
    #pragma unroll
    for (int j = 0; j < 8; ++j) Pacc[j] = 0.f;
    for (int r = 0; r < 4; ++r) {
        float sw = awv[r] / asum;
        int kv = kvs[r];
        bool sel[8];
        #pragma unroll
        for (int j = 0; j < 8; ++j) sel[j] = false;
        for (int m = 0; m < kv; ++m) {     // exact top_k: ties -> smallest index
            int best = 0; float bv = -3.4e38f;
            for (int j = 0; j < 8; ++j)
                if (!sel[j] && attn[j] > bv) { bv = attn[j]; best = j; }
            sel[best] = true;
        }
        float mx = -3.4e38f;
        for (int j = 0; j < 8; ++j) if (sel[j]) mx = fmaxf(mx, attn[j]);
        float es = 0.f, e[8];
        for (int j = 0; j < 8; ++j) { e[j] = sel[j] ? expf(attn[j] - mx) : 0.f; es += e[j]; }
        for (int j = 0; j < 8; ++j) Pacc[j] += sw * e[j] / es;
    }
    for (int j = 0; j < 8; ++j) P[t * 8 + j] = Pacc[j];
}

// ---------------- K4b: expand P to block-diagonal 64x64 A-frags ----------------
__global__ void k4b_pfrag(const float* __restrict__ P, short* __restrict__ PA) {
    int idx = blockIdx.x * 256 + threadIdx.x;   // 8192 = 2b x 2t x 4m x 64l x 8e
    int e = idx & 7, l = (idx >> 3) & 63, m = (idx >> 9) & 3;
    int t = (idx >> 11) & 1, b = idx >> 12;
    int out = 16*m + (l & 15), k = 32*t + ((l >> 4) << 3) + e;
    float v = ((k >> 3) == (out >> 3)) ? P[(b * 64 + out) * 8 + (k & 7)] : 0.f;
    PA[idx] = f2bf(v);
}

// ---------------- K5: fused tail via bf16 MFMA (v in bf16) ----------------
__global__ __launch_bounds__(256) void k5_tail(
        const short* __restrict__ qkv2, const float* __restrict__ x,
        const short* __restrict__ PA, const short* __restrict__ WrA,
        const short* __restrict__ WfA, const short* __restrict__ WpA,
        const float* __restrict__ bias1, const float* __restrict__ bias2,
        const float* __restrict__ bp, float* __restrict__ out) {
    __shared__ __align__(16) float As[64 * 64];
    __shared__ __align__(16) float Xs[64 * 64];
    const int tid = threadIdx.x, lane = tid & 63, wv = tid >> 6;
    const int blk = blockIdx.x;
    const int b = blk >> 10, n0 = (blk & 1023) << 6;
    const short* vg = qkv2 + ((long long)b * 192 + 128) * NPOS + n0;
    const float* xg = x + ((long long)b * 64) * NPOS + n0;
    #pragma unroll
    for (int kk = 0; kk < 4; ++kk) {
        int idx = tid + kk * 256;            // [64ch][64pos] float4 tiles
        int ch = idx >> 4, p = (idx & 15) << 2;
        *(float4*)(Xs + ch * 64 + p) = *(const float4*)(xg + (long long)ch * NPOS + p);
    }
    #pragma unroll
    for (int kk = 0; kk < 2; ++kk) {         // v: 512 chunks of 8 bf16
        int i = tid + kk * 256;
        int ch = i >> 3, p0 = (i & 7) << 3;
        bf16x8 raw = *(const bf16x8*)(vg + (long long)ch * NPOS + p0);
        *(float4*)(As + ch * 64 + p0) =
            make_float4(bf2f(raw[0]), bf2f(raw[1]), bf2f(raw[2]), bf2f(raw[3]));
        *(float4*)(As + ch * 64 + p0 + 4) =
            make_float4(bf2f(raw[4]), bf2f(raw[5]), bf2f(raw[6]), bf2f(raw[7]));
    }
    bf16x8 pA[2][4];
    #pragma unroll
    for (int t = 0; t < 2; ++t)
        #pragma unroll
        for (int m = 0; m < 4; ++m)
            pA[t][m] = *(const bf16x8*)(PA + (((b * 2 + t) * 4 + m) * 64 + lane) * 8);
    const int bcol  = wv * 16 + (lane & 15);   // B col / D col
    const int bk    = (lane >> 4) << 3;        // B/A k-slice base
    const int drow0 = (lane >> 4) << 2;        // D row base within 16-tile
    __syncthreads();

    auto loadB = [&](const float* S, int kbase) {
        bf16x8 r;
        #pragma unroll
        for (int e = 0; e < 8; ++e) r[e] = f2bf(S[(kbase + bk + e) * 64 + bcol]);
        return r;
    };

    // ---- stage1: weighted = P_blockdiag @ v
    f32x4 Dw[4];
    {
        bf16x8 B0 = loadB(As, 0), B1 = loadB(As, 32);
        #pragma unroll
        for (int m = 0; m < 4; ++m) {
            f32x4 a = {0.f, 0.f, 0.f, 0.f};
            a = __builtin_amdgcn_mfma_f32_16x16x32_bf16(pA[0][m], B0, a, 0, 0, 0);
            a = __builtin_amdgcn_mfma_f32_16x16x32_bf16(pA[1][m], B1, a, 0, 0, 0);
            Dw[m] = a;
        }
    }
    __syncthreads();
    #pragma unroll
    for (int m = 0; m < 4; ++m)
        #pragma unroll
        for (int r = 0; r < 4; ++r)
            As[(16 * m + drow0 + r) * 64 + bcol] = Dw[m][r];
    __syncthreads();

    // ---- stage2: rec = sigmoid(Wr'@weighted + bias1); enh = weighted*rec
    float enh[4][4];
    {
        bf16x8 rA[2][4];
        #pragma unroll
        for (int t = 0; t < 2; ++t)
            #pragma unroll
            for (int m = 0; m < 4; ++m)
                rA[t][m] = *(const bf16x8*)(WrA + ((t * 4 + m) * 64 + lane) * 8);
        bf16x8 B0 = loadB(As, 0), B1 = loadB(As, 32);
        #pragma unroll
        for (int m = 0; m < 4; ++m) {
            f32x4 a = {0.f, 0.f, 0.f, 0.f};
            a = __builtin_amdgcn_mfma_f32_16x16x32_bf16(rA[0][m], B0, a, 0, 0, 0);
            a = __builtin_amdgcn_mfma_f32_16x16x32_bf16(rA[1][m], B1, a, 0, 0, 0);
            #pragma unroll
            for (int r = 0; r < 4; ++r) {
                float z = a[r] + bias1[16 * m + drow0 + r];
                enh[m][r] = Dw[m][r] / (1.f + expf(-z));
            }
        }
    }
    __syncthreads();
    #pragma unroll
    for (int m = 0; m < 4; ++m)
        #pragma unroll
        for (int r = 0; r < 4; ++r)
            As[(16 * m + drow0 + r) * 64 + bcol] = enh[m][r];
    __syncthreads();

    // ---- stage3: fusz = Wf'@[enh; x] + bias2
    f32x4 D3[4];
    {
        bf16x8 fA[4][4];
        #pragma unroll
        for (int t = 0; t < 4; ++t)
            #pragma unroll
            for (int m = 0; m < 4; ++m)
                fA[t][m] = *(const bf16x8*)(WfA + ((t * 4 + m) * 64 + lane) * 8);
        bf16x8 B0 = loadB(As, 0), B1 = loadB(As, 32);
        bf16x8 B2 = loadB(Xs, 0), B3 = loadB(Xs, 32);
        #pragma unroll
        for (int m = 0; m < 4; ++m) {
            f32x4 a = {0.f, 0.f, 0.f, 0.f};
            a = __builtin_amdgcn_mfma_f32_16x16x32_bf16(fA[0][m], B0, a, 0, 0, 0);
            a = __builtin_amdgcn_mfma_f32_16x16x32_bf16(fA[1][m], B1, a, 0, 0, 0);
            a = __builtin_amdgcn_mfma_f32_16x16x32_bf16(fA[2][m], B2, a, 0, 0, 0);
            a = __builtin_amdgcn_mfma_f32_16x16x32_bf16(fA[3][m], B3, a, 0, 0, 0);
            #pragma unroll
            for (int r = 0; r < 4; ++r) a[r] += bias2[16 * m + drow0 + r];
            D3[m] = a;
        }
    }
    __syncthreads();
    #pragma unroll
    for (int m = 0; m < 4; ++m)
        #pragma unroll
        for (int r = 0; r < 4; ++r)
            As[(16 * m + drow0 + r) * 64 + bcol] = D3[m][r];
    __syncthreads();

    // ---- stage4: out = Wp@fusz + bp
    f32x4 D4[4];
    {
        bf16x8 qA[2][4];
        #pragma unroll
        for (int t = 0; t < 2; ++t)
            #pragma unroll
            for (int m = 0; m < 4; ++m)
                qA[t][m] = *(const bf16x8*)(WpA + ((t * 4 + m) * 64 + lane) * 8);
        bf16x8 B0 = loadB(As, 0), B1 = loadB(As, 32);
        #pragma unroll
        for (int m = 0; m < 4; ++m) {
            f32x4 a = {0.f, 0.f, 0.f, 0.f};
            a = __builtin_amdgcn_mfma_f32_16x16x32_bf16(qA[0][m], B0, a, 0, 0, 0);
            a = __builtin_amdgcn_mfma_f32_16x16x32_bf16(qA[1][m], B1, a, 0, 0, 0);
            #pragma unroll
            for (int r = 0; r < 4; ++r) a[r] += bp[16 * m + drow0 + r];
            D4[m] = a;
        }
    }
    __syncthreads();
    #pragma unroll
    for (int m = 0; m < 4; ++m)
        #pragma unroll
        for (int r = 0; r < 4; ++r)
            As[(16 * m + drow0 + r) * 64 + bcol] = D4[m][r];
    __syncthreads();
    // coalesced store: thread -> (row = tid>>2, 16 pos)
    const int row = tid >> 2, q = tid & 3;
    #pragma unroll
    for (int j = 0; j < 4; ++j) {
        int p = q * 4 + j * 16;
        *(float4*)(out + ((long long)b * 64 + row) * NPOS + n0 + p) =
            *(const float4*)(As + row * 64 + p);
    }
}

extern "C" void kernel_launch(void* const* d_in, const int* in_sizes, int n_in,
                              void* d_out, int out_size, void* d_ws, size_t ws_size,
                              hipStream_t stream) {
    (void)in_sizes; (void)n_in; (void)out_size; (void)ws_size;
    const float* x     = (const float*)d_in[0];
    const float* w_qkv = (const float*)d_in[1];
    const float* b_qkv = (const float*)d_in[2];
    const float* w_dw  = (const float*)d_in[3];
    const float* b_dw  = (const float*)d_in[4];
    const float* temp  = (const float*)d_in[5];
    const float* aw    = (const float*)d_in[6];
    const float* w_rec = (const float*)d_in[7];
    const float* b_rec = (const float*)d_in[8];
    const float* bn1g  = (const float*)d_in[9];
    const float* bn1b  = (const float*)d_in[10];
    const float* w_fus = (const float*)d_in[11];
    const float* b_fus = (const float*)d_in[12];
    const float* bn2g  = (const float*)d_in[13];
    const float* bn2b  = (const float*)d_in[14];
    const float* w_prj = (const float*)d_in[15];
    const float* b_prj = (const float*)d_in[16];
    float* out = (float*)d_out;

    short* qkv  = (short*)d_ws;             // 25165824 bf16 (50.3 MB)
    short* qkv2 = qkv + 25165824;           // 25165824 bf16
    float* part = (float*)(qkv2 + 25165824);// 16*128*80 = 163840 f32
    float* gram = part + 163840;            // 1280
    float* P    = gram + 1280;              // 1024
    float* bias1 = P + 1024;                // 64
    float* bias2 = bias1 + 64;              // 64
    short* WqA  = (short*)(bias2 + 64);     // 12288 shorts
    short* WrA  = WqA + 12288;              // 4096 shorts
    short* WfA  = WrA + 4096;               // 8192 shorts
    short* WpA  = WfA + 8192;               // 4096 shorts
    short* PAb  = WpA + 4096;               // 8192 shorts

    k0_prep<<<113, 256, 0, stream>>>(w_qkv, w_rec, w_fus, w_prj, b_rec, bn1g, bn1b,
                                     b_fus, bn2g, bn2b, WqA, WrA, WfA, WpA, bias1, bias2);
    k1_qkv<<<2048, 256, 0, stream>>>(x, WqA, b_qkv, qkv);
    k2_dw<<<6144, 256, 0, stream>>>(qkv, w_dw, b_dw, qkv2);
    k3_gram<<<16 * NCHUNK, 256, 0, stream>>>(qkv2, part);
    k3b_reduce<<<5, 256, 0, stream>>>(part, gram);
    k4_combine<<<1, 128, 0, stream>>>(gram, temp, aw, P);
    k4b_pfrag<<<32, 256, 0, stream>>>(P, PAb);
    k5_tail<<<2048, 256, 0, stream>>>(qkv2, x, PAb, WrA, WfA, WpA,
                                      bias1, bias2, b_prj, out);
}

// Round 11
// 113.753 us; speedup vs baseline: 2.8131x; 1.4533x over previous
//
#include <hip/hip_runtime.h>
#include <math.h>

#define NPOS 65536          // D*H*W = 16*64*64
#define DD 16
#define HHH 64
#define WWW 64
#define K3CHUNK 64

typedef __attribute__((ext_vector_type(8))) short bf16x8;   // 8 bf16 (4 VGPR)
typedef __attribute__((ext_vector_type(4))) short s16x4;
typedef __attribute__((ext_vector_type(4))) float f32x4;

static __device__ __forceinline__ short f2bf(float f) {
    union { float f; unsigned u; } v; v.f = f;
    unsigned r = (v.u + 0x7FFFu + ((v.u >> 16) & 1u)) >> 16;
    return (short)r;
}
static __device__ __forceinline__ float bf2f(short s) {
    union { unsigned u; float f; } v; v.u = ((unsigned)(unsigned short)s) << 16;
    return v.f;
}

// ---------------- K0: MFMA A-frag weight prep (BN folded) ----------------
__global__ void k0_prep(const float* __restrict__ Wq,
                        const float* __restrict__ Wr, const float* __restrict__ Wf,
                        const float* __restrict__ Wp,
                        const float* __restrict__ brec,
                        const float* __restrict__ bn1g, const float* __restrict__ bn1b,
                        const float* __restrict__ bfus,
                        const float* __restrict__ bn2g, const float* __restrict__ bn2b,
                        short* __restrict__ WqA, short* __restrict__ WrA,
                        short* __restrict__ WfA, short* __restrict__ WpA,
                        float* __restrict__ bias1, float* __restrict__ bias2) {
    const float invs = 1.0f / sqrtf(1.0f + 1e-5f);
    int idx = blockIdx.x * 256 + threadIdx.x;
    if (idx < 12288) {   // WqA: 3 chunks x 2 K-tiles x 4 M-tiles
        int e = idx & 7, l = (idx >> 3) & 63, m = (idx >> 9) & 3;
        int t = (idx >> 11) & 1, c = idx >> 12;
        int out = c*64 + 16*m + (l & 15), k = 32*t + ((l >> 4) << 3) + e;
        WqA[idx] = f2bf(Wq[out*64 + k]);
        return;
    }
    int i = idx - 12288;
    if (i < 4096) {      // WrA
        int e = i & 7, l = (i >> 3) & 63, m = (i >> 9) & 3, t = (i >> 11) & 1;
        int out = 16*m + (l & 15), k = 32*t + ((l >> 4) << 3) + e;
        WrA[i] = f2bf(Wr[out*64 + k] * bn1g[out] * invs);
        return;
    }
    i -= 4096;
    if (i < 8192) {      // WfA
        int e = i & 7, l = (i >> 3) & 63, m = (i >> 9) & 3, t = (i >> 11) & 3;
        int out = 16*m + (l & 15), k = 32*t + ((l >> 4) << 3) + e;
        WfA[i] = f2bf(Wf[out*128 + k] * bn2g[out] * invs);
        return;
    }
    i -= 8192;
    if (i < 4096) {      // WpA
        int e = i & 7, l = (i >> 3) & 63, m = (i >> 9) & 3, t = (i >> 11) & 1;
        int out = 16*m + (l & 15), k = 32*t + ((l >> 4) << 3) + e;
        WpA[i] = f2bf(Wp[out*64 + k]);
        return;
    }
    i -= 4096;
    if (i < 64)       bias1[i]    = brec[i]    * bn1g[i]    * invs + bn1b[i];
    else if (i < 128) bias2[i-64] = bfus[i-64] * bn2g[i-64] * invs + bn2b[i-64];
}

// ---------------- K1: pointwise qkv conv via bf16 MFMA (bf16 output) --------
__global__ __launch_bounds__(256) void k1_qkv(const float* __restrict__ x,
        const short* __restrict__ WqA, const float* __restrict__ bq,
        short* __restrict__ qkv) {
    __shared__ __align__(16) float Xs[64 * 64];
    __shared__ __align__(16) float As[64 * 64];
    const int tid = threadIdx.x, lane = tid & 63, wv = tid >> 6;
    const int blk = blockIdx.x;
    const int b = blk >> 10, n0 = (blk & 1023) << 6;
    const float* xg = x + ((long long)b * 64) * NPOS + n0;
    #pragma unroll
    for (int kk = 0; kk < 4; ++kk) {
        int idx = tid + kk * 256;
        int ch = idx >> 4, p = (idx & 15) << 2;
        *(float4*)(Xs + ch * 64 + p) = *(const float4*)(xg + (long long)ch * NPOS + p);
    }
    const int bcol  = wv * 16 + (lane & 15);
    const int bk    = (lane >> 4) << 3;
    const int drow0 = (lane >> 4) << 2;
    __syncthreads();

    bf16x8 B0, B1;
    #pragma unroll
    for (int e = 0; e < 8; ++e) B0[e] = f2bf(Xs[(bk + e) * 64 + bcol]);
    #pragma unroll
    for (int e = 0; e < 8; ++e) B1[e] = f2bf(Xs[(32 + bk + e) * 64 + bcol]);

    #pragma unroll
    for (int c = 0; c < 3; ++c) {
        f32x4 D[4];
        #pragma unroll
        for (int m = 0; m < 4; ++m) {
            bf16x8 A0 = *(const bf16x8*)(WqA + (((c * 2 + 0) * 4 + m) * 64 + lane) * 8);
            bf16x8 A1 = *(const bf16x8*)(WqA + (((c * 2 + 1) * 4 + m) * 64 + lane) * 8);
            f32x4 a = {0.f, 0.f, 0.f, 0.f};
            a = __builtin_amdgcn_mfma_f32_16x16x32_bf16(A0, B0, a, 0, 0, 0);
            a = __builtin_amdgcn_mfma_f32_16x16x32_bf16(A1, B1, a, 0, 0, 0);
            float4 bb = *(const float4*)(bq + c * 64 + 16 * m + drow0);
            a[0] += bb.x; a[1] += bb.y; a[2] += bb.z; a[3] += bb.w;
            D[m] = a;
        }
        if (c) __syncthreads();
        #pragma unroll
        for (int m = 0; m < 4; ++m)
            #pragma unroll
            for (int r = 0; r < 4; ++r)
                As[(16 * m + drow0 + r) * 64 + bcol] = D[m][r];
        __syncthreads();
        const int row = tid >> 2, q = tid & 3;
        bf16x8 o0, o1;
        #pragma unroll
        for (int j = 0; j < 8; ++j) {
            o0[j] = f2bf(As[row * 64 + q * 16 + j]);
            o1[j] = f2bf(As[row * 64 + q * 16 + 8 + j]);
        }
        short* op = qkv + ((long long)b * 192 + c * 64 + row) * NPOS + n0 + q * 16;
        *(bf16x8*)(op)     = o0;
        *(bf16x8*)(op + 8) = o1;
    }
}

// ---------------- K2: depthwise 3x3x3 conv, bf16 in/out, shuffle edges ------
__global__ __launch_bounds__(256) void k2_dw(const short* __restrict__ qkv,
        const float* __restrict__ Wd, const float* __restrict__ bd,
        short* __restrict__ qkv2) {
    __shared__ __align__(16) float tile[108 * 72];
    __shared__ float wsh[28];
    const int tid = threadIdx.x;
    const int lane = tid & 63;
    const int bc  = blockIdx.x >> 4;        // 0..383 = b*192 + c
    const int sub = blockIdx.x & 15;
    const int d0  = (sub >> 2) << 2;        // 0,4,8,12
    const int h0  = (sub & 3) << 4;         // 0,16,32,48
    const int c   = bc % 192;

    if (tid < 27) wsh[tid] = Wd[c * 27 + tid];
    if (tid == 31) wsh[27] = bd[c];

    const short* in = qkv + (long long)bc * NPOS;
    for (int i = tid; i < 864; i += 256) {   // 108 rows x 8 chunks of 8 bf16
        const int r = i >> 3, q8 = i & 7;
        const int dd = r / 18;               // 0..5
        const int hh = r - dd * 18;          // 0..17
        const int d = d0 + dd - 1;
        const int h = h0 + hh - 1;
        float4 f0 = make_float4(0.f, 0.f, 0.f, 0.f);
        float4 f1 = make_float4(0.f, 0.f, 0.f, 0.f);
        if (d >= 0 && d < DD && h >= 0 && h < HHH) {
            bf16x8 raw = *(const bf16x8*)(in + (d << 12) + (h << 6) + (q8 << 3));
            f0 = make_float4(bf2f(raw[0]), bf2f(raw[1]), bf2f(raw[2]), bf2f(raw[3]));
            f1 = make_float4(bf2f(raw[4]), bf2f(raw[5]), bf2f(raw[6]), bf2f(raw[7]));
        }
        *(float4*)(tile + r * 72 + (q8 << 3))     = f0;
        *(float4*)(tile + r * 72 + (q8 << 3) + 4) = f1;
    }
    __syncthreads();

    float wreg[27];
    #pragma unroll
    for (int s = 0; s < 27; ++s) wreg[s] = wsh[s];
    const float bias = wsh[27];

    const int wl = tid & 15;                // w-group: w0 = 4*wl
    const int oh = tid >> 4;                // 0..15
    const int w0 = wl << 2;

    float acc[4][4];                        // [od][j]
    #pragma unroll
    for (int od = 0; od < 4; ++od)
        #pragma unroll
        for (int j = 0; j < 4; ++j) acc[od][j] = bias;

    #pragma unroll
    for (int kh = 0; kh < 3; ++kh) {
        #pragma unroll
        for (int dp = 0; dp < 6; ++dp) {    // tile d-plane (abs d = d0+dp-1)
            const float* row = tile + (dp * 18 + oh + kh) * 72 + w0;
            const float4 v = *(const float4*)(row);
            float lf = __shfl(v.w, lane - 1, 64);
            float rt = __shfl(v.x, lane + 1, 64);
            lf = (wl == 0)  ? 0.f : lf;     // w=-1 zero pad
            rt = (wl == 15) ? 0.f : rt;     // w=64 zero pad
            const float win[6] = {lf, v.x, v.y, v.z, v.w, rt};
            #pragma unroll
            for (int od = 0; od < 4; ++od) {
                const int kd = dp - od;     // plane dp feeds od with kd=dp-od
                if (kd < 0 || kd > 2) continue;
                const float W0 = wreg[kd * 9 + kh * 3 + 0];
                const float W1 = wreg[kd * 9 + kh * 3 + 1];
                const float W2 = wreg[kd * 9 + kh * 3 + 2];
                #pragma unroll
                for (int j = 0; j < 4; ++j)
                    acc[od][j] = fmaf(W0, win[j],
                                 fmaf(W1, win[j+1], fmaf(W2, win[j+2], acc[od][j])));
            }
        }
    }
    short* outp = qkv2 + (long long)bc * NPOS + (h0 + oh) * 64 + w0;
    #pragma unroll
    for (int od = 0; od < 4; ++od) {
        s16x4 o;
        #pragma unroll
        for (int j = 0; j < 4; ++j) o[j] = f2bf(acc[od][j]);
        *(s16x4*)(outp + ((d0 + od) << 12)) = o;
    }
}

// ---------------- K3: Gram via MFMA: G16 = [q;k] @ [q;k]^T ----------------
// For mfma_f32_16x16x32_bf16 with B = A^T, the A- and B-fragments are the
// SAME registers: lane l holds M[ch=l&15][pos0+(l>>4)*8+e] (contiguous 16B).
// One mfma per 32 positions computes the whole 16x16 Gram tile (qk block +
// qq/kk diagonals). Grid: 16 bh x 64 chunks; 4 waves x 256 pos each.
__global__ __launch_bounds__(256) void k3_gram(const short* __restrict__ qkv2,
                                               float* __restrict__ partial) {
    const int blk = blockIdx.x;
    const int chunk = blk & (K3CHUNK - 1);
    const int bh = blk >> 6;                  // 0..15
    const int b = bh >> 3, h = bh & 7;
    const int tid = threadIdx.x, lane = tid & 63, wv = tid >> 6;
    const short* base = qkv2 + ((long long)b * 192 + h * 8) * NPOS;
    const int ch = lane & 15;
    const long long roff = (ch < 8 ? (long long)ch : (long long)(56 + ch)) * NPOS;
    const short* p = base + roff + chunk * 1024 + wv * 256 + ((lane >> 4) << 3);

    f32x4 a0 = {0.f, 0.f, 0.f, 0.f}, a1 = {0.f, 0.f, 0.f, 0.f};
    #pragma unroll
    for (int it = 0; it < 4; ++it) {
        bf16x8 f0 = *(const bf16x8*)(p + it * 64);
        bf16x8 f1 = *(const bf16x8*)(p + it * 64 + 32);
        a0 = __builtin_amdgcn_mfma_f32_16x16x32_bf16(f0, f0, a0, 0, 0, 0);
        a1 = __builtin_amdgcn_mfma_f32_16x16x32_bf16(f1, f1, a1, 0, 0, 0);
    }
    // cross-wave reduce of the 16x16 tile (C/D: col=lane&15, row=(lane>>4)*4+r)
    __shared__ float gs[4][256];
    #pragma unroll
    for (int r = 0; r < 4; ++r)
        gs[wv][(((lane >> 4) << 2) + r) * 16 + (lane & 15)] = a0[r] + a1[r];
    __syncthreads();
    const int row = tid >> 4, col = tid & 15;
    float v = gs[0][tid] + gs[1][tid] + gs[2][tid] + gs[3][tid];
    float* pp = partial + ((long long)bh * K3CHUNK + chunk) * 80;
    if (row < 8 && col >= 8)      pp[row * 8 + (col - 8)] = v;   // qk
    else if (row == col && row < 8) pp[64 + row] = v;            // qq
    else if (row == col)            pp[72 + row - 8] = v;        // kk
}

// ---------------- K3b: deterministic chunk reduction ----------------
__global__ void k3b_reduce(const float* __restrict__ partial, float* __restrict__ gram) {
    int s = blockIdx.x * 256 + threadIdx.x;
    if (s >= 16 * 80) return;
    int bh = s / 80, slot = s % 80;
    float acc = 0.f;
    for (int c = 0; c < K3CHUNK; ++c)
        acc += partial[((long long)bh * K3CHUNK + c) * 80 + slot];
    gram[s] = acc;
}

// ---------------- K4: attn -> topk mask softmax -> combined P ----------------
__global__ void k4_combine(const float* __restrict__ gram, const float* __restrict__ temp,
                           const float* __restrict__ aw, float* __restrict__ P) {
    int t = threadIdx.x;               // one (b,h,i) row per thread; 128 threads
    if (t >= 128) return;
    int bh = t >> 3, i = t & 7;
    int h = bh & 7;
    const float* g = gram + bh * 80;
    float qn = fmaxf(sqrtf(g[64 + i]), 1e-12f);
    float tp = temp[h];
    float attn[8];
    #pragma unroll
    for (int j = 0; j < 8; ++j) {
        float kn = fmaxf(sqrtf(g[72 + j]), 1e-12f);
        attn[j] = g[i * 8 + j] / (qn * kn) * tp;
    }
    float awv[4];
    float am = -3.4e38f;
    for (int r = 0; r < 4; ++r) { awv[r] = aw[r]; am = fmaxf(am, awv[r]); }
    float asum = 0.f;
    for (int r = 0; r < 4; ++r) { awv[r] = expf(awv[r] - am); asum += awv[r]; }
    const int kvs[4] = {4, 5, 6, 6};   // int(8*ratio) for 0.5,0.67,0.75,0.8
    float Pacc[8];
    #pragma unroll
    for (int j = 0; j < 8; ++j) Pacc[j] = 0.f;
    for (int r = 0; r < 4; ++r) {
        float sw = awv[r] / asum;
        int kv = kvs[r];
        bool sel[8];
        #pragma unroll
        for (int j = 0; j < 8; ++j) sel[j] = false;
        for (int m = 0; m < kv; ++m) {     // exact top_k: ties -> smallest index
            int best = 0; float bv = -3.4e38f;
            for (int j = 0; j < 8; ++j)
                if (!sel[j] && attn[j] > bv) { bv = attn[j]; best = j; }
            sel[best] = true;
        }
        float mx = -3.4e38f;
        for (int j = 0; j < 8; ++j) if (sel[j]) mx = fmaxf(mx, attn[j]);
        float es = 0.f, e[8];
        for (int j = 0; j < 8; ++j) { e[j] = sel[j] ? expf(attn[j] - mx) : 0.f; es += e[j]; }
        for (int j = 0; j < 8; ++j) Pacc[j] += sw * e[j] / es;
    }
    for (int j = 0; j < 8; ++j) P[t * 8 + j] = Pacc[j];
}

// ---------------- K4b: expand P to block-diagonal 64x64 A-frags ----------------
__global__ void k4b_pfrag(const float* __restrict__ P, short* __restrict__ PA) {
    int idx = blockIdx.x * 256 + threadIdx.x;   // 8192 = 2b x 2t x 4m x 64l x 8e
    int e = idx & 7, l = (idx >> 3) & 63, m = (idx >> 9) & 3;
    int t = (idx >> 11) & 1, b = idx >> 12;
    int out = 16*m + (l & 15), k = 32*t + ((l >> 4) << 3) + e;
    float v = ((k >> 3) == (out >> 3)) ? P[(b * 64 + out) * 8 + (k & 7)] : 0.f;
    PA[idx] = f2bf(v);
}

// ---------------- K5: fused tail via bf16 MFMA (v in bf16) ----------------
__global__ __launch_bounds__(256) void k5_tail(
        const short* __restrict__ qkv2, const float* __restrict__ x,
        const short* __restrict__ PA, const short* __restrict__ WrA,
        const short* __restrict__ WfA, const short* __restrict__ WpA,
        const float* __restrict__ bias1, const float* __restrict__ bias2,
        const float* __restrict__ bp, float* __restrict__ out) {
    __shared__ __align__(16) float As[64 * 64];
    __shared__ __align__(16) float Xs[64 * 64];
    const int tid = threadIdx.x, lane = tid & 63, wv = tid >> 6;
    const int blk = blockIdx.x;
    const int b = blk >> 10, n0 = (blk & 1023) << 6;
    const short* vg = qkv2 + ((long long)b * 192 + 128) * NPOS + n0;
    const float* xg = x + ((long long)b * 64) * NPOS + n0;
    #pragma unroll
    for (int kk = 0; kk < 4; ++kk) {
        int idx = tid + kk * 256;            // [64ch][64pos] float4 tiles
        int ch = idx >> 4, p = (idx & 15) << 2;
        *(float4*)(Xs + ch * 64 + p) = *(const float4*)(xg + (long long)ch * NPOS + p);
    }
    #pragma unroll
    for (int kk = 0; kk < 2; ++kk) {         // v: 512 chunks of 8 bf16
        int i = tid + kk * 256;
        int ch = i >> 3, p0 = (i & 7) << 3;
        bf16x8 raw = *(const bf16x8*)(vg + (long long)ch * NPOS + p0);
        *(float4*)(As + ch * 64 + p0) =
            make_float4(bf2f(raw[0]), bf2f(raw[1]), bf2f(raw[2]), bf2f(raw[3]));
        *(float4*)(As + ch * 64 + p0 + 4) =
            make_float4(bf2f(raw[4]), bf2f(raw[5]), bf2f(raw[6]), bf2f(raw[7]));
    }
    bf16x8 pA[2][4];
    #pragma unroll
    for (int t = 0; t < 2; ++t)
        #pragma unroll
        for (int m = 0; m < 4; ++m)
            pA[t][m] = *(const bf16x8*)(PA + (((b * 2 + t) * 4 + m) * 64 + lane) * 8);
    const int bcol  = wv * 16 + (lane & 15);   // B col / D col
    const int bk    = (lane >> 4) << 3;        // B/A k-slice base
    const int drow0 = (lane >> 4) << 2;        // D row base within 16-tile
    __syncthreads();

    auto loadB = [&](const float* S, int kbase) {
        bf16x8 r;
        #pragma unroll
        for (int e = 0; e < 8; ++e) r[e] = f2bf(S[(kbase + bk + e) * 64 + bcol]);
        return r;
    };

    // ---- stage1: weighted = P_blockdiag @ v
    f32x4 Dw[4];
    {
        bf16x8 B0 = loadB(As, 0), B1 = loadB(As, 32);
        #pragma unroll
        for (int m = 0; m < 4; ++m) {
            f32x4 a = {0.f, 0.f, 0.f, 0.f};
            a = __builtin_amdgcn_mfma_f32_16x16x32_bf16(pA[0][m], B0, a, 0, 0, 0);
            a = __builtin_amdgcn_mfma_f32_16x16x32_bf16(pA[1][m], B1, a, 0, 0, 0);
            Dw[m] = a;
        }
    }
    __syncthreads();
    #pragma unroll
    for (int m = 0; m < 4; ++m)
        #pragma unroll
        for (int r = 0; r < 4; ++r)
            As[(16 * m + drow0 + r) * 64 + bcol] = Dw[m][r];
    __syncthreads();

    // ---- stage2: rec = sigmoid(Wr'@weighted + bias1); enh = weighted*rec
    float enh[4][4];
    {
        bf16x8 rA[2][4];
        #pragma unroll
        for (int t = 0; t < 2; ++t)
            #pragma unroll
            for (int m = 0; m < 4; ++m)
                rA[t][m] = *(const bf16x8*)(WrA + ((t * 4 + m) * 64 + lane) * 8);
        bf16x8 B0 = loadB(As, 0), B1 = loadB(As, 32);
        #pragma unroll
        for (int m = 0; m < 4; ++m) {
            f32x4 a = {0.f, 0.f, 0.f, 0.f};
            a = __builtin_amdgcn_mfma_f32_16x16x32_bf16(rA[0][m], B0, a, 0, 0, 0);
            a = __builtin_amdgcn_mfma_f32_16x16x32_bf16(rA[1][m], B1, a, 0, 0, 0);
            #pragma unroll
            for (int r = 0; r < 4; ++r) {
                float z = a[r] + bias1[16 * m + drow0 + r];
                enh[m][r] = Dw[m][r] / (1.f + expf(-z));
            }
        }
    }
    __syncthreads();
    #pragma unroll
    for (int m = 0; m < 4; ++m)
        #pragma unroll
        for (int r = 0; r < 4; ++r)
            As[(16 * m + drow0 + r) * 64 + bcol] = enh[m][r];
    __syncthreads();

    // ---- stage3: fusz = Wf'@[enh; x] + bias2
    f32x4 D3[4];
    {
        bf16x8 fA[4][4];
        #pragma unroll
        for (int t = 0; t < 4; ++t)
            #pragma unroll
            for (int m = 0; m < 4; ++m)
                fA[t][m] = *(const bf16x8*)(WfA + ((t * 4 + m) * 64 + lane) * 8);
        bf16x8 B0 = loadB(As, 0), B1 = loadB(As, 32);
        bf16x8 B2 = loadB(Xs, 0), B3 = loadB(Xs, 32);
        #pragma unroll
        for (int m = 0; m < 4; ++m) {
            f32x4 a = {0.f, 0.f, 0.f, 0.f};
            a = __builtin_amdgcn_mfma_f32_16x16x32_bf16(fA[0][m], B0, a, 0, 0, 0);
            a = __builtin_amdgcn_mfma_f32_16x16x32_bf16(fA[1][m], B1, a, 0, 0, 0);
            a = __builtin_amdgcn_mfma_f32_16x16x32_bf16(fA[2][m], B2, a, 0, 0, 0);
            a = __builtin_amdgcn_mfma_f32_16x16x32_bf16(fA[3][m], B3, a, 0, 0, 0);
            #pragma unroll
            for (int r = 0; r < 4; ++r) a[r] += bias2[16 * m + drow0 + r];
            D3[m] = a;
        }
    }
    __syncthreads();
    #pragma unroll
    for (int m = 0; m < 4; ++m)
        #pragma unroll
        for (int r = 0; r < 4; ++r)
            As[(16 * m + drow0 + r) * 64 + bcol] = D3[m][r];
    __syncthreads();

    // ---- stage4: out = Wp@fusz + bp
    f32x4 D4[4];
    {
        bf16x8 qA[2][4];
        #pragma unroll
        for (int t = 0; t < 2; ++t)
            #pragma unroll
            for (int m = 0; m < 4; ++m)
                qA[t][m] = *(const bf16x8*)(WpA + ((t * 4 + m) * 64 + lane) * 8);
        bf16x8 B0 = loadB(As, 0), B1 = loadB(As, 32);
        #pragma unroll
        for (int m = 0; m < 4; ++m) {
            f32x4 a = {0.f, 0.f, 0.f, 0.f};
            a = __builtin_amdgcn_mfma_f32_16x16x32_bf16(qA[0][m], B0, a, 0, 0, 0);
            a = __builtin_amdgcn_mfma_f32_16x16x32_bf16(qA[1][m], B1, a, 0, 0, 0);
            #pragma unroll
            for (int r = 0; r < 4; ++r) a[r] += bp[16 * m + drow0 + r];
            D4[m] = a;
        }
    }
    __syncthreads();
    #pragma unroll
    for (int m = 0; m < 4; ++m)
        #pragma unroll
        for (int r = 0; r < 4; ++r)
            As[(16 * m + drow0 + r) * 64 + bcol] = D4[m][r];
    __syncthreads();
    // coalesced store: thread -> (row = tid>>2, 16 pos)
    const int row = tid >> 2, q = tid & 3;
    #pragma unroll
    for (int j = 0; j < 4; ++j) {
        int p = q * 4 + j * 16;
        *(float4*)(out + ((long long)b * 64 + row) * NPOS + n0 + p) =
            *(const float4*)(As + row * 64 + p);
    }
}

extern "C" void kernel_launch(void* const* d_in, const int* in_sizes, int n_in,
                              void* d_out, int out_size, void* d_ws, size_t ws_size,
                              hipStream_t stream) {
    (void)in_sizes; (void)n_in; (void)out_size; (void)ws_size;
    const float* x     = (const float*)d_in[0];
    const float* w_qkv = (const float*)d_in[1];
    const float* b_qkv = (const float*)d_in[2];
    const float* w_dw  = (const float*)d_in[3];
    const float* b_dw  = (const float*)d_in[4];
    const float* temp  = (const float*)d_in[5];
    const float* aw    = (const float*)d_in[6];
    const float* w_rec = (const float*)d_in[7];
    const float* b_rec = (const float*)d_in[8];
    const float* bn1g  = (const float*)d_in[9];
    const float* bn1b  = (const float*)d_in[10];
    const float* w_fus = (const float*)d_in[11];
    const float* b_fus = (const float*)d_in[12];
    const float* bn2g  = (const float*)d_in[13];
    const float* bn2b  = (const float*)d_in[14];
    const float* w_prj = (const float*)d_in[15];
    const float* b_prj = (const float*)d_in[16];
    float* out = (float*)d_out;

    short* qkv  = (short*)d_ws;             // 25165824 bf16 (50.3 MB)
    short* qkv2 = qkv + 25165824;           // 25165824 bf16
    float* part = (float*)(qkv2 + 25165824);// 16*64*80 = 81920 f32
    float* gram = part + 163840;            // 1280
    float* P    = gram + 1280;              // 1024
    float* bias1 = P + 1024;                // 64
    float* bias2 = bias1 + 64;              // 64
    short* WqA  = (short*)(bias2 + 64);     // 12288 shorts
    short* WrA  = WqA + 12288;              // 4096 shorts
    short* WfA  = WrA + 4096;               // 8192 shorts
    short* WpA  = WfA + 8192;               // 4096 shorts
    short* PAb  = WpA + 4096;               // 8192 shorts

    k0_prep<<<113, 256, 0, stream>>>(w_qkv, w_rec, w_fus, w_prj, b_rec, bn1g, bn1b,
                                     b_fus, bn2g, bn2b, WqA, WrA, WfA, WpA, bias1, bias2);
    k1_qkv<<<2048, 256, 0, stream>>>(x, WqA, b_qkv, qkv);
    k2_dw<<<6144, 256, 0, stream>>>(qkv, w_dw, b_dw, qkv2);
    k3_gram<<<16 * K3CHUNK, 256, 0, stream>>>(qkv2, part);
    k3b_reduce<<<5, 256, 0, stream>>>(part, gram);
    k4_combine<<<1, 128, 0, stream>>>(gram, temp, aw, P);
    k4b_pfrag<<<32, 256, 0, stream>>>(P, PAb);
    k5_tail<<<2048, 256, 0, stream>>>(qkv2, x, PAb, WrA, WfA, WpA,
                                      bias1, bias2, b_prj, out);
}